// Round 1
// baseline (5634.865 us; speedup 1.0000x reference)
//
#include <hip/hip_runtime.h>
#include <hip/hip_bf16.h>
#include <math.h>

#define V_NODES 3000
#define K_DEG 16
#define E_EDGES 48000
#define H 256
#define TE 128
#define L_LAYERS 12

// ---------------------------------------------------------------------------
// multi-row block mean/var (LayerNorm stats) over H=256 columns, 256 threads
// red must hold RB*H floats.
// ---------------------------------------------------------------------------
template <int RB>
__device__ __forceinline__ void rows_meanvar(const float (&v)[RB], float* red,
                                             float (&outm)[RB], float (&outvar)[RB], int j) {
#pragma unroll
  for (int r = 0; r < RB; ++r) red[r * H + j] = v[r];
  __syncthreads();
  for (int st = 128; st > 0; st >>= 1) {
    if (j < st) {
#pragma unroll
      for (int r = 0; r < RB; ++r) red[r * H + j] += red[r * H + j + st];
    }
    __syncthreads();
  }
  float m[RB];
#pragma unroll
  for (int r = 0; r < RB; ++r) m[r] = red[r * H] * (1.0f / H);
  __syncthreads();
#pragma unroll
  for (int r = 0; r < RB; ++r) {
    float d = v[r] - m[r];
    red[r * H + j] = d * d;
  }
  __syncthreads();
  for (int st = 128; st > 0; st >>= 1) {
    if (j < st) {
#pragma unroll
      for (int r = 0; r < RB; ++r) red[r * H + j] += red[r * H + j + st];
    }
    __syncthreads();
  }
#pragma unroll
  for (int r = 0; r < RB; ++r) {
    outm[r] = m[r];
    outvar[r] = red[r * H] * (1.0f / H);
  }
  __syncthreads();
}

// ---------------------------------------------------------------------------
// Node positional embedding + node_w matmul: x[v] = posembed(coords[v]) @ W + b
// ---------------------------------------------------------------------------
__global__ __launch_bounds__(256) void k_node_embed(const float* __restrict__ coords,
                                                    const float* __restrict__ W,
                                                    const float* __restrict__ b,
                                                    float* __restrict__ x) {
  int v = blockIdx.x;
  int j = threadIdx.x;
  __shared__ float4 pe4[H / 4];
  float cy = coords[v * 2 + 0] * 6.283185307179586f;
  float cx = coords[v * 2 + 1] * 6.283185307179586f;
  int idx = j & 127;
  float coord = (j < 128) ? cy : cx;
  float dim_t = powf(10000.0f, (2.0f * (float)(idx >> 1)) / 128.0f);
  float val = coord / dim_t;
  ((float*)pe4)[j] = (idx & 1) ? cosf(val) : sinf(val);
  __syncthreads();
  float acc = b[j];
  for (int k4 = 0; k4 < H / 4; ++k4) {
    float4 p = pe4[k4];
    int k = 4 * k4;
    acc += p.x * W[(k + 0) * H + j] + p.y * W[(k + 1) * H + j] +
           p.z * W[(k + 2) * H + j] + p.w * W[(k + 3) * H + j];
  }
  x[(size_t)v * H + j] = acc;
}

// ---------------------------------------------------------------------------
// Edge scalar embedding + edge_w matmul + mask embedding
// ---------------------------------------------------------------------------
template <int RB>
__global__ __launch_bounds__(256) void k_edge_embed(const float* __restrict__ e_vals,
                                                    const int* __restrict__ mask,
                                                    const float* __restrict__ W,
                                                    const float* __restrict__ b,
                                                    const float* __restrict__ mask_emb,
                                                    float* __restrict__ e) {
  int e0 = blockIdx.x * RB;
  int j = threadIdx.x;
  __shared__ float4 pe4[RB][H / 4];
  float dim_t = powf(10000.0f, (2.0f * (float)(j >> 1)) / 256.0f);
  bool is_odd = (j & 1);
#pragma unroll
  for (int r = 0; r < RB; ++r) {
    float val = e_vals[e0 + r] / dim_t;
    ((float*)&pe4[r][0])[j] = is_odd ? cosf(val) : sinf(val);
  }
  __syncthreads();
  float acc[RB];
#pragma unroll
  for (int r = 0; r < RB; ++r) acc[r] = b[j] + mask_emb[mask[e0 + r] * H + j];
  for (int k4 = 0; k4 < H / 4; ++k4) {
    int k = 4 * k4;
    float w0 = W[(k + 0) * H + j], w1 = W[(k + 1) * H + j];
    float w2 = W[(k + 2) * H + j], w3 = W[(k + 3) * H + j];
#pragma unroll
    for (int r = 0; r < RB; ++r) {
      float4 p = pe4[r][k4];
      acc[r] += p.x * w0 + p.y * w1 + p.z * w2 + p.w * w3;
    }
  }
#pragma unroll
  for (int r = 0; r < RB; ++r) e[(size_t)(e0 + r) * H + j] = acc[r];
}

// ---------------------------------------------------------------------------
// Timestep embedding MLP (single block)
// ---------------------------------------------------------------------------
__global__ __launch_bounds__(256) void k_temb(const int* __restrict__ t,
                                              const float* __restrict__ te1_w,
                                              const float* __restrict__ te1_b,
                                              const float* __restrict__ te2_w,
                                              const float* __restrict__ te2_b,
                                              float* __restrict__ temb_out) {
  __shared__ float emb[H];
  __shared__ float h1[TE];
  int j = threadIdx.x;
  float tv = (float)t[0];
  {
    int i = j & 127;
    float f = expf(-logf(10000.0f) * (float)i / 128.0f);
    float arg = tv * f;
    emb[j] = (j < 128) ? cosf(arg) : sinf(arg);
  }
  __syncthreads();
  if (j < TE) {
    float acc = te1_b[j];
    for (int k = 0; k < H; ++k) acc += emb[k] * te1_w[k * TE + j];
    h1[j] = fmaxf(acc, 0.0f);
  }
  __syncthreads();
  if (j < TE) {
    float acc = te2_b[j];
    for (int k = 0; k < TE; ++k) acc += h1[k] * te2_w[k * TE + j];
    temb_out[j] = acc;
  }
}

// ---------------------------------------------------------------------------
// Per-layer conditioning vector: tvec[l] = relu(temb) @ tl_w[l] + tl_b[l]
// ---------------------------------------------------------------------------
__global__ __launch_bounds__(256) void k_tvec(const float* __restrict__ temb,
                                              const float* __restrict__ tl_w,
                                              const float* __restrict__ tl_b,
                                              float* __restrict__ tvec) {
  int l = blockIdx.x;
  int j = threadIdx.x;
  __shared__ float rt[TE];
  if (j < TE) rt[j] = fmaxf(temb[j], 0.0f);
  __syncthreads();
  float acc = tl_b[l * H + j];
  for (int k = 0; k < TE; ++k) acc += rt[k] * tl_w[(size_t)(l * TE + k) * H + j];
  tvec[l * H + j] = acc;
}

// ---------------------------------------------------------------------------
// Node-level matmuls: Uh/Vh/Ah/Bh = x @ {U,V,A,B}_w + bias   (one block/node)
// ---------------------------------------------------------------------------
__global__ __launch_bounds__(256) void k_node_mats(const float* __restrict__ x,
                                                   const float* __restrict__ Uw, const float* __restrict__ Ub,
                                                   const float* __restrict__ Vw, const float* __restrict__ Vb,
                                                   const float* __restrict__ Aw, const float* __restrict__ Ab,
                                                   const float* __restrict__ Bw, const float* __restrict__ Bb,
                                                   float* __restrict__ Uh, float* __restrict__ Vh,
                                                   float* __restrict__ Ah, float* __restrict__ Bh) {
  int v = blockIdx.x;
  int j = threadIdx.x;
  __shared__ float4 xs4[H / 4];
  ((float*)xs4)[j] = x[(size_t)v * H + j];
  __syncthreads();
  float au = Ub[j], av = Vb[j], aa = Ab[j], ab = Bb[j];
  for (int k4 = 0; k4 < H / 4; ++k4) {
    float4 xv = xs4[k4];
    int k = 4 * k4;
    au += xv.x * Uw[(k + 0) * H + j] + xv.y * Uw[(k + 1) * H + j] +
          xv.z * Uw[(k + 2) * H + j] + xv.w * Uw[(k + 3) * H + j];
    av += xv.x * Vw[(k + 0) * H + j] + xv.y * Vw[(k + 1) * H + j] +
          xv.z * Vw[(k + 2) * H + j] + xv.w * Vw[(k + 3) * H + j];
    aa += xv.x * Aw[(k + 0) * H + j] + xv.y * Aw[(k + 1) * H + j] +
          xv.z * Aw[(k + 2) * H + j] + xv.w * Aw[(k + 3) * H + j];
    ab += xv.x * Bw[(k + 0) * H + j] + xv.y * Bw[(k + 1) * H + j] +
          xv.z * Bw[(k + 2) * H + j] + xv.w * Bw[(k + 3) * H + j];
  }
  size_t o = (size_t)v * H + j;
  Uh[o] = au; Vh[o] = av; Ah[o] = aa; Bh[o] = ab;
}

// ---------------------------------------------------------------------------
// Edge e_new = (e @ C_w + C_b) + Ah[col] + Bh[row]
// ---------------------------------------------------------------------------
template <int RB>
__global__ __launch_bounds__(256) void k_edge_new(const float* __restrict__ e,
                                                  const float* __restrict__ Cw, const float* __restrict__ Cb,
                                                  const float* __restrict__ Ah, const float* __restrict__ Bh,
                                                  const int* __restrict__ ei_row, const int* __restrict__ ei_col,
                                                  float* __restrict__ e_new) {
  int e0 = blockIdx.x * RB;
  int j = threadIdx.x;
  __shared__ float4 es4[RB][H / 4];
#pragma unroll
  for (int r = 0; r < RB; ++r) ((float*)&es4[r][0])[j] = e[(size_t)(e0 + r) * H + j];
  __syncthreads();
  float acc[RB];
  float cb = Cb[j];
#pragma unroll
  for (int r = 0; r < RB; ++r) acc[r] = cb;
  for (int k4 = 0; k4 < H / 4; ++k4) {
    int k = 4 * k4;
    float w0 = Cw[(k + 0) * H + j], w1 = Cw[(k + 1) * H + j];
    float w2 = Cw[(k + 2) * H + j], w3 = Cw[(k + 3) * H + j];
#pragma unroll
    for (int r = 0; r < RB; ++r) {
      float4 ev = es4[r][k4];
      acc[r] += ev.x * w0 + ev.y * w1 + ev.z * w2 + ev.w * w3;
    }
  }
#pragma unroll
  for (int r = 0; r < RB; ++r) {
    int eid = e0 + r;
    e_new[(size_t)eid * H + j] = acc[r] + Ah[(size_t)ei_col[eid] * H + j] + Bh[(size_t)ei_row[eid] * H + j];
  }
}

// ---------------------------------------------------------------------------
// Node update: agg = sum_k sigmoid(e_new[v,k])*Vh[col]; x += relu(LN(Uh+agg))
// ---------------------------------------------------------------------------
__global__ __launch_bounds__(256) void k_node_update(const float* __restrict__ e_new,
                                                     const float* __restrict__ Vh,
                                                     const float* __restrict__ Uh,
                                                     const int* __restrict__ ei_col,
                                                     const float* __restrict__ nhg,
                                                     const float* __restrict__ nhb,
                                                     float* __restrict__ x) {
  int v = blockIdx.x;
  int j = threadIdx.x;
  float agg = 0.0f;
#pragma unroll 4
  for (int k = 0; k < K_DEG; ++k) {
    int eid = v * K_DEG + k;
    float en = e_new[(size_t)eid * H + j];
    float g = 1.0f / (1.0f + expf(-en));
    agg += g * Vh[(size_t)ei_col[eid] * H + j];
  }
  float s = Uh[(size_t)v * H + j] + agg;
  __shared__ float red[H];
  float sv[1] = {s};
  float m[1], var[1];
  rows_meanvar<1>(sv, red, m, var, j);
  float h = (s - m[0]) * rsqrtf(var[0] + 1e-5f) * nhg[j] + nhb[j];
  x[(size_t)v * H + j] += fmaxf(h, 0.0f);
}

// ---------------------------------------------------------------------------
// Edge finish: a = relu(LN(e_new))+tvec ; b = silu(LN(a)) ; e += b@plo_w+plo_b2
// ---------------------------------------------------------------------------
template <int RB>
__global__ __launch_bounds__(256) void k_edge_finish(const float* __restrict__ e_new,
                                                     const float* __restrict__ neg_, const float* __restrict__ neb_,
                                                     const float* __restrict__ tvec_l,
                                                     const float* __restrict__ pg_, const float* __restrict__ pb_,
                                                     const float* __restrict__ plo_w, const float* __restrict__ plo_b2,
                                                     float* __restrict__ e) {
  int e0 = blockIdx.x * RB;
  int j = threadIdx.x;
  __shared__ float red[RB * H];
  __shared__ float4 bs4[RB][H / 4];
  float v1[RB];
#pragma unroll
  for (int r = 0; r < RB; ++r) v1[r] = e_new[(size_t)(e0 + r) * H + j];
  float m[RB], var[RB];
  rows_meanvar<RB>(v1, red, m, var, j);
  float a[RB];
  float neg = neg_[j], neb = neb_[j], tv = tvec_l[j];
#pragma unroll
  for (int r = 0; r < RB; ++r) {
    float n = (v1[r] - m[r]) * rsqrtf(var[r] + 1e-5f) * neg + neb;
    a[r] = fmaxf(n, 0.0f) + tv;
  }
  rows_meanvar<RB>(a, red, m, var, j);
  float pg = pg_[j], pb = pb_[j];
#pragma unroll
  for (int r = 0; r < RB; ++r) {
    float n = (a[r] - m[r]) * rsqrtf(var[r] + 1e-5f) * pg + pb;
    float s = n / (1.0f + expf(-n));  // silu
    ((float*)&bs4[r][0])[j] = s;
  }
  __syncthreads();
  float acc[RB];
  float pb2 = plo_b2[j];
#pragma unroll
  for (int r = 0; r < RB; ++r) acc[r] = pb2;
  for (int k4 = 0; k4 < H / 4; ++k4) {
    int k = 4 * k4;
    float w0 = plo_w[(k + 0) * H + j], w1 = plo_w[(k + 1) * H + j];
    float w2 = plo_w[(k + 2) * H + j], w3 = plo_w[(k + 3) * H + j];
#pragma unroll
    for (int r = 0; r < RB; ++r) {
      float4 bv = bs4[r][k4];
      acc[r] += bv.x * w0 + bv.y * w1 + bv.z * w2 + bv.w * w3;
    }
  }
#pragma unroll
  for (int r = 0; r < RB; ++r) e[(size_t)(e0 + r) * H + j] += acc[r];
}

// ---------------------------------------------------------------------------
// GroupNorm stats: per-channel sum/sumsq in f64 (atomics), then per-group stats
// ---------------------------------------------------------------------------
__global__ __launch_bounds__(256) void k_gn_stats(const float* __restrict__ e, double* __restrict__ sums) {
  int j = threadIdx.x;
  int b = blockIdx.x;
  double s = 0.0, sq = 0.0;
  for (int row = b; row < E_EDGES; row += gridDim.x) {
    float v = e[(size_t)row * H + j];
    s += (double)v;
    sq += (double)v * (double)v;
  }
  atomicAdd(&sums[j], s);
  atomicAdd(&sums[H + j], sq);
}

__global__ void k_gn_finalize(const double* __restrict__ sums, float* __restrict__ gstats) {
  int g = threadIdx.x;
  if (g < 32) {
    double s = 0.0, sq = 0.0;
    for (int c = g * 8; c < g * 8 + 8; ++c) {
      s += sums[c];
      sq += sums[H + c];
    }
    double n = 8.0 * (double)E_EDGES;
    double mean = s / n;
    double var = sq / n - mean * mean;
    gstats[g] = (float)mean;
    gstats[32 + g] = (float)(1.0 / sqrt(var + 1e-5));
  }
}

// ---------------------------------------------------------------------------
// Head: out[e,o] = sum_c relu(GN(e[e,c])) * out_w[c,o] + out_b[o]
// one wave per edge (4 edges / 256-thread block)
// ---------------------------------------------------------------------------
__global__ __launch_bounds__(256) void k_head(const float* __restrict__ e,
                                              const float* __restrict__ gstats,
                                              const float* __restrict__ gn_g, const float* __restrict__ gn_b,
                                              const float* __restrict__ out_w, const float* __restrict__ out_b,
                                              float* __restrict__ out) {
  int wv = threadIdx.x >> 6;
  int lane = threadIdx.x & 63;
  int eid = blockIdx.x * 4 + wv;
  int c0 = lane * 4;
  float4 ev = *(const float4*)&e[(size_t)eid * H + c0];
  float vv[4] = {ev.x, ev.y, ev.z, ev.w};
  float a0 = 0.0f, a1 = 0.0f;
#pragma unroll
  for (int i = 0; i < 4; ++i) {
    int c = c0 + i;
    int g = c >> 3;
    float v = (vv[i] - gstats[g]) * gstats[32 + g] * gn_g[c] + gn_b[c];
    v = fmaxf(v, 0.0f);
    a0 += v * out_w[c * 2 + 0];
    a1 += v * out_w[c * 2 + 1];
  }
  for (int s = 32; s > 0; s >>= 1) {
    a0 += __shfl_down(a0, s);
    a1 += __shfl_down(a1, s);
  }
  if (lane == 0) {
    out[(size_t)eid * 2 + 0] = a0 + out_b[0];
    out[(size_t)eid * 2 + 1] = a1 + out_b[1];
  }
}

// ---------------------------------------------------------------------------
extern "C" void kernel_launch(void* const* d_in, const int* in_sizes, int n_in,
                              void* d_out, int out_size, void* d_ws, size_t ws_size,
                              hipStream_t stream) {
  const float* nodes_feature = (const float*)d_in[0];
  const float* e_vals = (const float*)d_in[1];
  const int* mask = (const int*)d_in[2];
  const int* t = (const int*)d_in[3];
  const int* edge_index = (const int*)d_in[4];
  const float* node_w = (const float*)d_in[5];
  const float* node_b = (const float*)d_in[6];
  const float* edge_w = (const float*)d_in[7];
  const float* edge_b = (const float*)d_in[8];
  const float* te1_w = (const float*)d_in[9];
  const float* te1_b = (const float*)d_in[10];
  const float* te2_w = (const float*)d_in[11];
  const float* te2_b = (const float*)d_in[12];
  const float* U_w = (const float*)d_in[13];
  const float* U_b = (const float*)d_in[14];
  const float* V_w = (const float*)d_in[15];
  const float* V_b = (const float*)d_in[16];
  const float* A_w = (const float*)d_in[17];
  const float* A_b = (const float*)d_in[18];
  const float* B_w = (const float*)d_in[19];
  const float* B_b = (const float*)d_in[20];
  const float* C_w = (const float*)d_in[21];
  const float* C_b = (const float*)d_in[22];
  const float* nh_g = (const float*)d_in[23];
  const float* nh_b = (const float*)d_in[24];
  const float* ne_g = (const float*)d_in[25];
  const float* ne_b = (const float*)d_in[26];
  const float* tl_w = (const float*)d_in[27];
  const float* tl_b = (const float*)d_in[28];
  const float* plo_g = (const float*)d_in[29];
  const float* plo_b = (const float*)d_in[30];
  const float* plo_w = (const float*)d_in[31];
  const float* plo_b2 = (const float*)d_in[32];
  const float* gn_g = (const float*)d_in[33];
  const float* gn_b = (const float*)d_in[34];
  const float* out_w = (const float*)d_in[35];
  const float* out_b = (const float*)d_in[36];
  const float* mask_emb = (const float*)d_in[37];

  char* wsb = (char*)d_ws;
  size_t off = 0;
  auto alloc = [&](size_t bytes) -> void* {
    void* p = wsb + off;
    off += (bytes + 255) & ~(size_t)255;
    return p;
  };
  double* gn_sums = (double*)alloc(512 * sizeof(double));
  float* x = (float*)alloc((size_t)V_NODES * H * 4);
  float* Uh = (float*)alloc((size_t)V_NODES * H * 4);
  float* Vh = (float*)alloc((size_t)V_NODES * H * 4);
  float* Ah = (float*)alloc((size_t)V_NODES * H * 4);
  float* Bh = (float*)alloc((size_t)V_NODES * H * 4);
  float* e = (float*)alloc((size_t)E_EDGES * H * 4);
  float* e_new = (float*)alloc((size_t)E_EDGES * H * 4);
  float* temb = (float*)alloc(TE * 4);
  float* tvec = (float*)alloc((size_t)L_LAYERS * H * 4);
  float* gstats = (float*)alloc(64 * 4);

  const int* ei_row = edge_index;
  const int* ei_col = edge_index + E_EDGES;

  k_node_embed<<<V_NODES, 256, 0, stream>>>(nodes_feature, node_w, node_b, x);
  k_edge_embed<8><<<E_EDGES / 8, 256, 0, stream>>>(e_vals, mask, edge_w, edge_b, mask_emb, e);
  k_temb<<<1, 256, 0, stream>>>(t, te1_w, te1_b, te2_w, te2_b, temb);
  k_tvec<<<L_LAYERS, 256, 0, stream>>>(temb, tl_w, tl_b, tvec);

  for (int l = 0; l < L_LAYERS; ++l) {
    size_t wo = (size_t)l * H * H;
    size_t bo = (size_t)l * H;
    k_node_mats<<<V_NODES, 256, 0, stream>>>(x, U_w + wo, U_b + bo, V_w + wo, V_b + bo,
                                             A_w + wo, A_b + bo, B_w + wo, B_b + bo,
                                             Uh, Vh, Ah, Bh);
    k_edge_new<8><<<E_EDGES / 8, 256, 0, stream>>>(e, C_w + wo, C_b + bo, Ah, Bh, ei_row, ei_col, e_new);
    k_node_update<<<V_NODES, 256, 0, stream>>>(e_new, Vh, Uh, ei_col, nh_g + bo, nh_b + bo, x);
    k_edge_finish<8><<<E_EDGES / 8, 256, 0, stream>>>(e_new, ne_g + bo, ne_b + bo, tvec + bo,
                                                      plo_g + bo, plo_b + bo, plo_w + wo, plo_b2 + bo, e);
  }

  hipMemsetAsync(gn_sums, 0, 512 * sizeof(double), stream);
  k_gn_stats<<<256, 256, 0, stream>>>(e, gn_sums);
  k_gn_finalize<<<1, 64, 0, stream>>>(gn_sums, gstats);
  float* out2 = (float*)d_out + (size_t)V_NODES * H;
  k_head<<<E_EDGES / 4, 256, 0, stream>>>(e, gstats, gn_g, gn_b, out_w, out_b, out2);
  hipMemcpyAsync(d_out, x, (size_t)V_NODES * H * sizeof(float), hipMemcpyDeviceToDevice, stream);
}

// Round 2
// 1423.074 us; speedup vs baseline: 3.9596x; 3.9596x over previous
//
#include <hip/hip_runtime.h>
#include <math.h>

#define V_NODES 3000
#define K_DEG 16
#define E_EDGES 48000
#define H 256
#define TE 128
#define L_LAYERS 12

typedef __attribute__((ext_vector_type(4))) float f32x4;
typedef __attribute__((ext_vector_type(8))) __bf16 bf16x8;
typedef __attribute__((ext_vector_type(4))) unsigned short u16x4;

__device__ __forceinline__ unsigned short f2bf(float f) {
  unsigned u = __float_as_uint(f);
  unsigned r = (u + 0x7fffu + ((u >> 16) & 1u)) >> 16;
  return (unsigned short)r;
}

__device__ __forceinline__ void gload16(const void* g, void* l) {
  __builtin_amdgcn_global_load_lds((const __attribute__((address_space(1))) void*)g,
                                   (__attribute__((address_space(3))) void*)l, 16, 0, 0);
}

// ---------------------------------------------------------------------------
// Weight prep: transpose 256x256 f32 [k][n] -> bf16 [n][k]; UVAB packed to
// [1024][256] per layer. 64x64 tiles per block.
// ---------------------------------------------------------------------------
__global__ __launch_bounds__(256) void k_prep_w(const float* __restrict__ U_w, const float* __restrict__ V_w,
                                                const float* __restrict__ A_w, const float* __restrict__ B_w,
                                                const float* __restrict__ C_w, const float* __restrict__ plo_w,
                                                const float* __restrict__ edge_w,
                                                unsigned short* __restrict__ WT4, unsigned short* __restrict__ WTC,
                                                unsigned short* __restrict__ WTplo, unsigned short* __restrict__ WTedge) {
  int bid = blockIdx.x;
  const float* src;
  unsigned short* dst;
  int tt;
  if (bid < 768) {  // UVAB: 12 layers x 4 mats x 16 tiles
    int l = bid >> 6;
    int rem = bid & 63;
    int mat = rem >> 4;
    tt = rem & 15;
    const float* srcs[4] = {U_w, V_w, A_w, B_w};
    src = srcs[mat] + (size_t)l * H * H;
    dst = WT4 + (size_t)l * 1024 * H + (size_t)mat * H * H;
  } else if (bid < 960) {  // C
    int b2 = bid - 768;
    int l = b2 >> 4;
    tt = b2 & 15;
    src = C_w + (size_t)l * H * H;
    dst = WTC + (size_t)l * H * H;
  } else if (bid < 1152) {  // plo
    int b2 = bid - 960;
    int l = b2 >> 4;
    tt = b2 & 15;
    src = plo_w + (size_t)l * H * H;
    dst = WTplo + (size_t)l * H * H;
  } else {  // edge_w
    tt = bid - 1152;
    src = edge_w;
    dst = WTedge;
  }
  int k0 = (tt & 3) * 64, n0 = (tt >> 2) * 64;
  __shared__ float ts[64][65];
  int c = threadIdx.x & 63;
  int r0 = threadIdx.x >> 6;
  for (int rr = 0; rr < 64; rr += 4) {
    int r = rr + r0;
    ts[r][c] = src[(size_t)(k0 + r) * H + n0 + c];
  }
  __syncthreads();
  for (int nn = 0; nn < 64; nn += 4) {
    int n = nn + r0;
    dst[(size_t)(n0 + n) * H + k0 + c] = f2bf(ts[c][n]);
  }
}

__global__ __launch_bounds__(256) void k_prep_b(const float* __restrict__ U_b, const float* __restrict__ V_b,
                                                const float* __restrict__ A_b, const float* __restrict__ B_b,
                                                float* __restrict__ b4) {
  int l = blockIdx.x;
  int t = threadIdx.x;
  b4[l * 1024 + 0 + t] = U_b[l * H + t];
  b4[l * 1024 + 256 + t] = V_b[l * H + t];
  b4[l * 1024 + 512 + t] = A_b[l * H + t];
  b4[l * 1024 + 768 + t] = B_b[l * H + t];
}

// ---------------------------------------------------------------------------
// MFMA GEMM: C(M x N) = A(M x 256) @ W(256 x N), A bf16 row-major, WT = W^T
// bf16 [N][256]. 128x128 tile/block, 4 waves of 64x64, BK=64, XOR-swizzled LDS.
// MODE 0: node UVAB   -> out_f32[m*1024+n] = acc + bias[n]
// MODE 1: edge e_new  -> acc + bias + Ah[col[m]] + Bh[m>>4]  (f32)
// MODE 2: edge plo    -> e += acc + bias; write e f32 + e bf16
// MODE 3: edge embed  -> acc + bias + mask_emb[mask[m]]; write e f32 + bf16
// ---------------------------------------------------------------------------
template <int MODE>
__global__ __launch_bounds__(256) void k_gemm(const unsigned short* __restrict__ A,
                                              const unsigned short* __restrict__ WT,
                                              int M,
                                              const float* __restrict__ bias,
                                              const int* __restrict__ ei_col,
                                              const int* __restrict__ maskp,
                                              const float* __restrict__ mask_emb,
                                              const float* __restrict__ XW,
                                              float* __restrict__ out_f32,
                                              unsigned short* __restrict__ out_bf16) {
  const int t = threadIdx.x;
  const int m0 = blockIdx.x * 128;
  const int nb = blockIdx.y * 128;
  const int lane = t & 63;
  const int wave = t >> 6;
  const int wr = wave >> 1, wc = wave & 1;
  const int lrow = lane & 15, lg = lane >> 4;

  __shared__ __align__(16) char lds[32768];
  char* Als = lds;          // [128 rows][128 bytes] (64 bf16), swizzled
  char* Bls = lds + 16384;  // same for W^T rows (n-dim)

  f32x4 acc[4][4];
#pragma unroll
  for (int i = 0; i < 4; ++i)
#pragma unroll
    for (int j = 0; j < 4; ++j) acc[i][j] = (f32x4)0.0f;

  for (int kt = 0; kt < 4; ++kt) {
    const int k0b = kt * 128;  // byte offset within 512B row
#pragma unroll
    for (int i = 0; i < 4; ++i) {
      int o = i * 4096 + t * 16;
      int row = o >> 7;
      int cb = o & 127;
      int cbl = cb ^ ((row & 7) << 4);
      int rA = m0 + row;
      rA = rA < M ? rA : 0;
      gload16((const char*)A + (size_t)rA * 512 + k0b + cbl,
              Als + i * 4096 + (t & 192) * 16);
      gload16((const char*)WT + (size_t)(nb + row) * 512 + k0b + cbl,
              Bls + i * 4096 + (t & 192) * 16);
    }
    __syncthreads();
#pragma unroll
    for (int ks = 0; ks < 2; ++ks) {
      bf16x8 af[4], bfv[4];
#pragma unroll
      for (int mi = 0; mi < 4; ++mi) {
        int ra = wr * 64 + mi * 16 + lrow;
        int cba = (ks * 64 + lg * 16) ^ ((ra & 7) << 4);
        af[mi] = *(const bf16x8*)(Als + ra * 128 + cba);
        int rb = wc * 64 + mi * 16 + lrow;
        int cbb = (ks * 64 + lg * 16) ^ ((rb & 7) << 4);
        bfv[mi] = *(const bf16x8*)(Bls + rb * 128 + cbb);
      }
#pragma unroll
      for (int mi = 0; mi < 4; ++mi)
#pragma unroll
        for (int ni = 0; ni < 4; ++ni)
          acc[mi][ni] = __builtin_amdgcn_mfma_f32_16x16x32_bf16(af[mi], bfv[ni], acc[mi][ni], 0, 0, 0);
    }
    __syncthreads();
  }

  // epilogue: D layout col = lane&15, row = (lane>>4)*4 + reg  [m89]
#pragma unroll
  for (int mi = 0; mi < 4; ++mi) {
#pragma unroll
    for (int r = 0; r < 4; ++r) {
      int m = m0 + wr * 64 + mi * 16 + lg * 4 + r;
      if (MODE == 0 && m >= M) continue;
      int cv = 0, rv = 0, mk = 0;
      if constexpr (MODE == 1) { cv = ei_col[m]; rv = m >> 4; }
      if constexpr (MODE == 3) { mk = maskp[m]; }
#pragma unroll
      for (int ni = 0; ni < 4; ++ni) {
        int n = nb + wc * 64 + ni * 16 + lrow;
        float v = acc[mi][ni][r] + bias[n];
        if constexpr (MODE == 0) {
          out_f32[(size_t)m * 1024 + n] = v;
        } else if constexpr (MODE == 1) {
          v += XW[(size_t)cv * 1024 + 512 + n] + XW[(size_t)rv * 1024 + 768 + n];
          out_f32[(size_t)m * 256 + n] = v;
        } else if constexpr (MODE == 2) {
          float r2 = out_f32[(size_t)m * 256 + n] + v;
          out_f32[(size_t)m * 256 + n] = r2;
          out_bf16[(size_t)m * 256 + n] = f2bf(r2);
        } else {
          v += mask_emb[mk * 256 + n];
          out_f32[(size_t)m * 256 + n] = v;
          out_bf16[(size_t)m * 256 + n] = f2bf(v);
        }
      }
    }
  }
}

// ---------------------------------------------------------------------------
// Node positional embedding + node_w matmul (small, stays VALU f32)
// ---------------------------------------------------------------------------
__global__ __launch_bounds__(256) void k_node_embed(const float* __restrict__ coords,
                                                    const float* __restrict__ W,
                                                    const float* __restrict__ b,
                                                    float* __restrict__ x,
                                                    unsigned short* __restrict__ xb) {
  int v = blockIdx.x;
  int j = threadIdx.x;
  __shared__ float4 pe4[H / 4];
  float cy = coords[v * 2 + 0] * 6.283185307179586f;
  float cx = coords[v * 2 + 1] * 6.283185307179586f;
  int idx = j & 127;
  float coord = (j < 128) ? cy : cx;
  float dim_t = powf(10000.0f, (2.0f * (float)(idx >> 1)) / 128.0f);
  float val = coord / dim_t;
  ((float*)pe4)[j] = (idx & 1) ? cosf(val) : sinf(val);
  __syncthreads();
  float acc = b[j];
  for (int k4 = 0; k4 < H / 4; ++k4) {
    float4 p = pe4[k4];
    int k = 4 * k4;
    acc += p.x * W[(k + 0) * H + j] + p.y * W[(k + 1) * H + j] +
           p.z * W[(k + 2) * H + j] + p.w * W[(k + 3) * H + j];
  }
  x[(size_t)v * H + j] = acc;
  xb[(size_t)v * H + j] = f2bf(acc);
}

// ---------------------------------------------------------------------------
// Edge scalar sine embedding -> pe bf16 [E][256]
// ---------------------------------------------------------------------------
__global__ __launch_bounds__(256) void k_pe(const float* __restrict__ e_vals, unsigned short* __restrict__ pe) {
  int eid = blockIdx.x * 4 + (threadIdx.x >> 6);
  int lane = threadIdx.x & 63;
  int c0 = lane * 4;
  float val = e_vals[eid];
  const float lg = 13.287712379549449f / 256.0f;  // log2(10000)/256
  u16x4 ov;
#pragma unroll
  for (int i = 0; i < 4; ++i) {
    int c = c0 + i;
    float invd = exp2f(-(float)(c & ~1) * lg);
    float arg = val * invd;
    float s = (c & 1) ? cosf(arg) : sinf(arg);
    ov[i] = f2bf(s);
  }
  *(u16x4*)&pe[(size_t)eid * H + c0] = ov;
}

// ---------------------------------------------------------------------------
// Timestep embedding MLP (single block)
// ---------------------------------------------------------------------------
__global__ __launch_bounds__(256) void k_temb(const int* __restrict__ t,
                                              const float* __restrict__ te1_w, const float* __restrict__ te1_b,
                                              const float* __restrict__ te2_w, const float* __restrict__ te2_b,
                                              float* __restrict__ temb_out) {
  __shared__ float emb[H];
  __shared__ float h1[TE];
  int j = threadIdx.x;
  float tv = (float)t[0];
  {
    int i = j & 127;
    float f = expf(-logf(10000.0f) * (float)i / 128.0f);
    float arg = tv * f;
    emb[j] = (j < 128) ? cosf(arg) : sinf(arg);
  }
  __syncthreads();
  if (j < TE) {
    float acc = te1_b[j];
    for (int k = 0; k < H; ++k) acc += emb[k] * te1_w[k * TE + j];
    h1[j] = fmaxf(acc, 0.0f);
  }
  __syncthreads();
  if (j < TE) {
    float acc = te2_b[j];
    for (int k = 0; k < TE; ++k) acc += h1[k] * te2_w[k * TE + j];
    temb_out[j] = acc;
  }
}

__global__ __launch_bounds__(256) void k_tvec(const float* __restrict__ temb,
                                              const float* __restrict__ tl_w, const float* __restrict__ tl_b,
                                              float* __restrict__ tvec) {
  int l = blockIdx.x;
  int j = threadIdx.x;
  __shared__ float rt[TE];
  if (j < TE) rt[j] = fmaxf(temb[j], 0.0f);
  __syncthreads();
  float acc = tl_b[l * H + j];
  for (int k = 0; k < TE; ++k) acc += rt[k] * tl_w[(size_t)(l * TE + k) * H + j];
  tvec[l * H + j] = acc;
}

// ---------------------------------------------------------------------------
// Node update: agg = sum_k sigmoid(e_new)*Vh[col]; x += relu(LN(Uh+agg))
// wave-per-node, lane holds 4 channels
// ---------------------------------------------------------------------------
__global__ __launch_bounds__(256) void k_node_update(const float* __restrict__ e_new,
                                                     const float* __restrict__ XW,
                                                     const int* __restrict__ ei_col,
                                                     const float* __restrict__ nhg, const float* __restrict__ nhb,
                                                     float* __restrict__ x, unsigned short* __restrict__ xb) {
  int v = blockIdx.x * 4 + (threadIdx.x >> 6);
  int lane = threadIdx.x & 63;
  int c0 = lane * 4;
  f32x4 agg = (f32x4)0.0f;
#pragma unroll 4
  for (int k = 0; k < K_DEG; ++k) {
    int eid = v * K_DEG + k;
    f32x4 en = *(const f32x4*)&e_new[(size_t)eid * H + c0];
    int cv = ei_col[eid];
    f32x4 vh = *(const f32x4*)&XW[(size_t)cv * 1024 + 256 + c0];
#pragma unroll
    for (int i = 0; i < 4; ++i) agg[i] += vh[i] / (1.0f + expf(-en[i]));
  }
  f32x4 s4 = *(const f32x4*)&XW[(size_t)v * 1024 + c0];  // Uh
  s4 += agg;
  float s = s4[0] + s4[1] + s4[2] + s4[3];
  float sq = s4[0] * s4[0] + s4[1] * s4[1] + s4[2] * s4[2] + s4[3] * s4[3];
#pragma unroll
  for (int st = 1; st < 64; st <<= 1) { s += __shfl_xor(s, st); sq += __shfl_xor(sq, st); }
  float mean = s * (1.0f / H);
  float inv = rsqrtf(sq * (1.0f / H) - mean * mean + 1e-5f);
  f32x4 g = *(const f32x4*)&nhg[c0];
  f32x4 bb = *(const f32x4*)&nhb[c0];
  f32x4 xo = *(const f32x4*)&x[(size_t)v * H + c0];
  u16x4 ov;
#pragma unroll
  for (int i = 0; i < 4; ++i) {
    float h = fmaxf((s4[i] - mean) * inv * g[i] + bb[i], 0.0f);
    xo[i] += h;
    ov[i] = f2bf(xo[i]);
  }
  *(f32x4*)&x[(size_t)v * H + c0] = xo;
  *(u16x4*)&xb[(size_t)v * H + c0] = ov;
}

// ---------------------------------------------------------------------------
// Edge LN chain: b = silu(LN2(relu(LN1(e_new))+tvec)), wave-per-row -> bf16
// ---------------------------------------------------------------------------
__global__ __launch_bounds__(256) void k_edge_ln(const float* __restrict__ e_new,
                                                 const float* __restrict__ neg_, const float* __restrict__ neb_,
                                                 const float* __restrict__ tvec_l,
                                                 const float* __restrict__ pg_, const float* __restrict__ pb_,
                                                 unsigned short* __restrict__ bout) {
  int eid = blockIdx.x * 4 + (threadIdx.x >> 6);
  int lane = threadIdx.x & 63;
  int c0 = lane * 4;
  f32x4 v = *(const f32x4*)&e_new[(size_t)eid * H + c0];
  float s = v[0] + v[1] + v[2] + v[3];
  float sq = v[0] * v[0] + v[1] * v[1] + v[2] * v[2] + v[3] * v[3];
#pragma unroll
  for (int st = 1; st < 64; st <<= 1) { s += __shfl_xor(s, st); sq += __shfl_xor(sq, st); }
  float mean = s * (1.0f / H);
  float inv = rsqrtf(sq * (1.0f / H) - mean * mean + 1e-5f);
  f32x4 g = *(const f32x4*)&neg_[c0];
  f32x4 bb = *(const f32x4*)&neb_[c0];
  f32x4 tv = *(const f32x4*)&tvec_l[c0];
  f32x4 a;
#pragma unroll
  for (int i = 0; i < 4; ++i) a[i] = fmaxf((v[i] - mean) * inv * g[i] + bb[i], 0.0f) + tv[i];
  s = a[0] + a[1] + a[2] + a[3];
  sq = a[0] * a[0] + a[1] * a[1] + a[2] * a[2] + a[3] * a[3];
#pragma unroll
  for (int st = 1; st < 64; st <<= 1) { s += __shfl_xor(s, st); sq += __shfl_xor(sq, st); }
  mean = s * (1.0f / H);
  inv = rsqrtf(sq * (1.0f / H) - mean * mean + 1e-5f);
  f32x4 g2 = *(const f32x4*)&pg_[c0];
  f32x4 b2 = *(const f32x4*)&pb_[c0];
  u16x4 ov;
#pragma unroll
  for (int i = 0; i < 4; ++i) {
    float n = (a[i] - mean) * inv * g2[i] + b2[i];
    float si = n / (1.0f + expf(-n));
    ov[i] = f2bf(si);
  }
  *(u16x4*)&bout[(size_t)eid * H + c0] = ov;
}

// ---------------------------------------------------------------------------
// GroupNorm stats + head (unchanged from round 1)
// ---------------------------------------------------------------------------
__global__ __launch_bounds__(256) void k_gn_stats(const float* __restrict__ e, double* __restrict__ sums) {
  int j = threadIdx.x;
  int b = blockIdx.x;
  double s = 0.0, sq = 0.0;
  for (int row = b; row < E_EDGES; row += gridDim.x) {
    float v = e[(size_t)row * H + j];
    s += (double)v;
    sq += (double)v * (double)v;
  }
  atomicAdd(&sums[j], s);
  atomicAdd(&sums[H + j], sq);
}

__global__ void k_gn_finalize(const double* __restrict__ sums, float* __restrict__ gstats) {
  int g = threadIdx.x;
  if (g < 32) {
    double s = 0.0, sq = 0.0;
    for (int c = g * 8; c < g * 8 + 8; ++c) {
      s += sums[c];
      sq += sums[H + c];
    }
    double n = 8.0 * (double)E_EDGES;
    double mean = s / n;
    double var = sq / n - mean * mean;
    gstats[g] = (float)mean;
    gstats[32 + g] = (float)(1.0 / sqrt(var + 1e-5));
  }
}

__global__ __launch_bounds__(256) void k_head(const float* __restrict__ e,
                                              const float* __restrict__ gstats,
                                              const float* __restrict__ gn_g, const float* __restrict__ gn_b,
                                              const float* __restrict__ out_w, const float* __restrict__ out_b,
                                              float* __restrict__ out) {
  int wv = threadIdx.x >> 6;
  int lane = threadIdx.x & 63;
  int eid = blockIdx.x * 4 + wv;
  int c0 = lane * 4;
  float4 ev = *(const float4*)&e[(size_t)eid * H + c0];
  float vv[4] = {ev.x, ev.y, ev.z, ev.w};
  float a0 = 0.0f, a1 = 0.0f;
#pragma unroll
  for (int i = 0; i < 4; ++i) {
    int c = c0 + i;
    int g = c >> 3;
    float v = (vv[i] - gstats[g]) * gstats[32 + g] * gn_g[c] + gn_b[c];
    v = fmaxf(v, 0.0f);
    a0 += v * out_w[c * 2 + 0];
    a1 += v * out_w[c * 2 + 1];
  }
  for (int s = 32; s > 0; s >>= 1) {
    a0 += __shfl_down(a0, s);
    a1 += __shfl_down(a1, s);
  }
  if (lane == 0) {
    out[(size_t)eid * 2 + 0] = a0 + out_b[0];
    out[(size_t)eid * 2 + 1] = a1 + out_b[1];
  }
}

// ---------------------------------------------------------------------------
extern "C" void kernel_launch(void* const* d_in, const int* in_sizes, int n_in,
                              void* d_out, int out_size, void* d_ws, size_t ws_size,
                              hipStream_t stream) {
  const float* nodes_feature = (const float*)d_in[0];
  const float* e_vals = (const float*)d_in[1];
  const int* mask = (const int*)d_in[2];
  const int* t = (const int*)d_in[3];
  const int* edge_index = (const int*)d_in[4];
  const float* node_w = (const float*)d_in[5];
  const float* node_b = (const float*)d_in[6];
  const float* edge_w = (const float*)d_in[7];
  const float* edge_b = (const float*)d_in[8];
  const float* te1_w = (const float*)d_in[9];
  const float* te1_b = (const float*)d_in[10];
  const float* te2_w = (const float*)d_in[11];
  const float* te2_b = (const float*)d_in[12];
  const float* U_w = (const float*)d_in[13];
  const float* U_b = (const float*)d_in[14];
  const float* V_w = (const float*)d_in[15];
  const float* V_b = (const float*)d_in[16];
  const float* A_w = (const float*)d_in[17];
  const float* A_b = (const float*)d_in[18];
  const float* B_w = (const float*)d_in[19];
  const float* B_b = (const float*)d_in[20];
  const float* C_w = (const float*)d_in[21];
  const float* C_b = (const float*)d_in[22];
  const float* nh_g = (const float*)d_in[23];
  const float* nh_b = (const float*)d_in[24];
  const float* ne_g = (const float*)d_in[25];
  const float* ne_b = (const float*)d_in[26];
  const float* tl_w = (const float*)d_in[27];
  const float* tl_b = (const float*)d_in[28];
  const float* plo_g = (const float*)d_in[29];
  const float* plo_b = (const float*)d_in[30];
  const float* plo_w = (const float*)d_in[31];
  const float* plo_b2 = (const float*)d_in[32];
  const float* gn_g = (const float*)d_in[33];
  const float* gn_b = (const float*)d_in[34];
  const float* out_w = (const float*)d_in[35];
  const float* out_b = (const float*)d_in[36];
  const float* mask_emb = (const float*)d_in[37];

  char* wsb = (char*)d_ws;
  size_t off = 0;
  auto alloc = [&](size_t bytes) -> void* {
    void* p = wsb + off;
    off += (bytes + 255) & ~(size_t)255;
    return p;
  };
  double* gn_sums = (double*)alloc(512 * sizeof(double));
  float* XW = (float*)alloc((size_t)V_NODES * 1024 * 4);          // U|V|A|B sections
  float* e = (float*)alloc((size_t)E_EDGES * H * 4);
  float* e_new = (float*)alloc((size_t)E_EDGES * H * 4);
  unsigned short* e_bf = (unsigned short*)alloc((size_t)E_EDGES * H * 2);
  unsigned short* pe_b = (unsigned short*)alloc((size_t)E_EDGES * H * 2);  // pe, reused as b
  unsigned short* x_bf = (unsigned short*)alloc((size_t)V_NODES * H * 2);
  unsigned short* WT4 = (unsigned short*)alloc((size_t)L_LAYERS * 1024 * H * 2);
  unsigned short* WTC = (unsigned short*)alloc((size_t)L_LAYERS * H * H * 2);
  unsigned short* WTplo = (unsigned short*)alloc((size_t)L_LAYERS * H * H * 2);
  unsigned short* WTedge = (unsigned short*)alloc((size_t)H * H * 2);
  float* b4 = (float*)alloc((size_t)L_LAYERS * 1024 * 4);
  float* temb = (float*)alloc(TE * 4);
  float* tvec = (float*)alloc((size_t)L_LAYERS * H * 4);
  float* gstats = (float*)alloc(64 * 4);

  const int* ei_col = edge_index + E_EDGES;

  float* x = (float*)d_out;  // x lives directly in d_out[0 : V*H)
  float* out2 = (float*)d_out + (size_t)V_NODES * H;

  k_prep_w<<<1168, 256, 0, stream>>>(U_w, V_w, A_w, B_w, C_w, plo_w, edge_w, WT4, WTC, WTplo, WTedge);
  k_prep_b<<<L_LAYERS, 256, 0, stream>>>(U_b, V_b, A_b, B_b, b4);
  k_node_embed<<<V_NODES, 256, 0, stream>>>(nodes_feature, node_w, node_b, x, x_bf);
  k_pe<<<E_EDGES / 4, 256, 0, stream>>>(e_vals, pe_b);
  k_temb<<<1, 256, 0, stream>>>(t, te1_w, te1_b, te2_w, te2_b, temb);
  k_tvec<<<L_LAYERS, 256, 0, stream>>>(temb, tl_w, tl_b, tvec);
  // e = pe @ edge_w + edge_b + mask_emb[mask]
  k_gemm<3><<<dim3(E_EDGES / 128, 2), 256, 0, stream>>>(pe_b, WTedge, E_EDGES, edge_b, nullptr, mask, mask_emb,
                                                        nullptr, e, e_bf);

  for (int l = 0; l < L_LAYERS; ++l) {
    size_t wo = (size_t)l * H * H;
    k_gemm<0><<<dim3(24, 8), 256, 0, stream>>>(x_bf, WT4 + (size_t)l * 1024 * H, V_NODES, b4 + l * 1024,
                                               nullptr, nullptr, nullptr, nullptr, XW, nullptr);
    k_gemm<1><<<dim3(E_EDGES / 128, 2), 256, 0, stream>>>(e_bf, WTC + wo, E_EDGES, C_b + l * H, ei_col,
                                                          nullptr, nullptr, XW, e_new, nullptr);
    k_node_update<<<V_NODES / 4, 256, 0, stream>>>(e_new, XW, ei_col, nh_g + l * H, nh_b + l * H, x, x_bf);
    k_edge_ln<<<E_EDGES / 4, 256, 0, stream>>>(e_new, ne_g + l * H, ne_b + l * H, tvec + l * H,
                                               plo_g + l * H, plo_b + l * H, pe_b);
    k_gemm<2><<<dim3(E_EDGES / 128, 2), 256, 0, stream>>>(pe_b, WTplo + wo, E_EDGES, plo_b2 + l * H,
                                                          nullptr, nullptr, nullptr, nullptr, e, e_bf);
  }

  hipMemsetAsync(gn_sums, 0, 512 * sizeof(double), stream);
  k_gn_stats<<<256, 256, 0, stream>>>(e, gn_sums);
  k_gn_finalize<<<1, 64, 0, stream>>>(gn_sums, gstats);
  k_head<<<E_EDGES / 4, 256, 0, stream>>>(e, gstats, gn_g, gn_b, out_w, out_b, out2);
}

// Round 3
// 1422.230 us; speedup vs baseline: 3.9620x; 1.0006x over previous
//
#include <hip/hip_runtime.h>
#include <math.h>

#define V_NODES 3000
#define K_DEG 16
#define E_EDGES 48000
#define H 256
#define TE 128
#define L_LAYERS 12

typedef __attribute__((ext_vector_type(4))) float f32x4;
typedef __attribute__((ext_vector_type(8))) __bf16 bf16x8;
typedef __attribute__((ext_vector_type(4))) unsigned short u16x4;

__device__ __forceinline__ unsigned short f2bf(float f) {
  unsigned u = __float_as_uint(f);
  unsigned r = (u + 0x7fffu + ((u >> 16) & 1u)) >> 16;
  return (unsigned short)r;
}

__device__ __forceinline__ void gload16(const void* g, void* l) {
  __builtin_amdgcn_global_load_lds((const __attribute__((address_space(1))) void*)g,
                                   (__attribute__((address_space(3))) void*)l, 16, 0, 0);
}

// ---------------------------------------------------------------------------
// Weight prep: transpose 256x256 f32 [k][n] -> bf16 [n][k]; UVAB packed to
// [1024][256] per layer.
// ---------------------------------------------------------------------------
__global__ __launch_bounds__(256) void k_prep_w(const float* __restrict__ U_w, const float* __restrict__ V_w,
                                                const float* __restrict__ A_w, const float* __restrict__ B_w,
                                                const float* __restrict__ C_w, const float* __restrict__ plo_w,
                                                const float* __restrict__ edge_w,
                                                unsigned short* __restrict__ WT4, unsigned short* __restrict__ WTC,
                                                unsigned short* __restrict__ WTplo, unsigned short* __restrict__ WTedge) {
  int bid = blockIdx.x;
  const float* src;
  unsigned short* dst;
  int tt;
  if (bid < 768) {
    int l = bid >> 6;
    int rem = bid & 63;
    int mat = rem >> 4;
    tt = rem & 15;
    const float* srcs[4] = {U_w, V_w, A_w, B_w};
    src = srcs[mat] + (size_t)l * H * H;
    dst = WT4 + (size_t)l * 1024 * H + (size_t)mat * H * H;
  } else if (bid < 960) {
    int b2 = bid - 768;
    int l = b2 >> 4;
    tt = b2 & 15;
    src = C_w + (size_t)l * H * H;
    dst = WTC + (size_t)l * H * H;
  } else if (bid < 1152) {
    int b2 = bid - 960;
    int l = b2 >> 4;
    tt = b2 & 15;
    src = plo_w + (size_t)l * H * H;
    dst = WTplo + (size_t)l * H * H;
  } else {
    tt = bid - 1152;
    src = edge_w;
    dst = WTedge;
  }
  int k0 = (tt & 3) * 64, n0 = (tt >> 2) * 64;
  __shared__ float ts[64][65];
  int c = threadIdx.x & 63;
  int r0 = threadIdx.x >> 6;
  for (int rr = 0; rr < 64; rr += 4) {
    int r = rr + r0;
    ts[r][c] = src[(size_t)(k0 + r) * H + n0 + c];
  }
  __syncthreads();
  for (int nn = 0; nn < 64; nn += 4) {
    int n = nn + r0;
    dst[(size_t)(n0 + n) * H + k0 + c] = f2bf(ts[c][n]);
  }
}

__global__ __launch_bounds__(256) void k_prep_b(const float* __restrict__ U_b, const float* __restrict__ V_b,
                                                const float* __restrict__ A_b, const float* __restrict__ B_b,
                                                float* __restrict__ b4) {
  int l = blockIdx.x;
  int t = threadIdx.x;
  b4[l * 1024 + 0 + t] = U_b[l * H + t];
  b4[l * 1024 + 256 + t] = V_b[l * H + t];
  b4[l * 1024 + 512 + t] = A_b[l * H + t];
  b4[l * 1024 + 768 + t] = B_b[l * H + t];
}

// ---------------------------------------------------------------------------
// Plain MFMA GEMM (128x128 tile, 4 waves, BK=64) for node-UVAB / plo / embed.
// MODE 0: node UVAB   -> out_f32[m*1024+n] = acc + bias[n]
// MODE 2: edge plo    -> e += acc + bias; write e f32 + e bf16
// MODE 3: edge embed  -> acc + bias + mask_emb[mask[m]]; write e f32 + bf16
// ---------------------------------------------------------------------------
template <int MODE>
__global__ __launch_bounds__(256) void k_gemm(const unsigned short* __restrict__ A,
                                              const unsigned short* __restrict__ WT,
                                              int M,
                                              const float* __restrict__ bias,
                                              const int* __restrict__ maskp,
                                              const float* __restrict__ mask_emb,
                                              float* __restrict__ out_f32,
                                              unsigned short* __restrict__ out_bf16) {
  const int t = threadIdx.x;
  const int m0 = blockIdx.x * 128;
  const int nb = blockIdx.y * 128;
  const int lane = t & 63;
  const int wave = t >> 6;
  const int wr = wave >> 1, wc = wave & 1;
  const int lrow = lane & 15, lg = lane >> 4;

  __shared__ __align__(16) char lds[32768];
  char* Als = lds;
  char* Bls = lds + 16384;

  f32x4 acc[4][4];
#pragma unroll
  for (int i = 0; i < 4; ++i)
#pragma unroll
    for (int j = 0; j < 4; ++j) acc[i][j] = (f32x4)0.0f;

  for (int kt = 0; kt < 4; ++kt) {
    const int k0b = kt * 128;
#pragma unroll
    for (int i = 0; i < 4; ++i) {
      int o = i * 4096 + t * 16;
      int row = o >> 7;
      int cb = o & 127;
      int cbl = cb ^ ((row & 7) << 4);
      int rA = m0 + row;
      rA = rA < M ? rA : 0;
      gload16((const char*)A + (size_t)rA * 512 + k0b + cbl,
              Als + i * 4096 + (t & 192) * 16);
      gload16((const char*)WT + (size_t)(nb + row) * 512 + k0b + cbl,
              Bls + i * 4096 + (t & 192) * 16);
    }
    __syncthreads();
#pragma unroll
    for (int ks = 0; ks < 2; ++ks) {
      bf16x8 af[4], bfv[4];
#pragma unroll
      for (int mi = 0; mi < 4; ++mi) {
        int ra = wr * 64 + mi * 16 + lrow;
        int cba = (ks * 64 + lg * 16) ^ ((ra & 7) << 4);
        af[mi] = *(const bf16x8*)(Als + ra * 128 + cba);
        int rb = wc * 64 + mi * 16 + lrow;
        int cbb = (ks * 64 + lg * 16) ^ ((rb & 7) << 4);
        bfv[mi] = *(const bf16x8*)(Bls + rb * 128 + cbb);
      }
#pragma unroll
      for (int mi = 0; mi < 4; ++mi)
#pragma unroll
        for (int ni = 0; ni < 4; ++ni)
          acc[mi][ni] = __builtin_amdgcn_mfma_f32_16x16x32_bf16(af[mi], bfv[ni], acc[mi][ni], 0, 0, 0);
    }
    __syncthreads();
  }

#pragma unroll
  for (int mi = 0; mi < 4; ++mi) {
#pragma unroll
    for (int r = 0; r < 4; ++r) {
      int m = m0 + wr * 64 + mi * 16 + lg * 4 + r;
      if (MODE == 0 && m >= M) continue;
      int mk = 0;
      if constexpr (MODE == 3) { mk = maskp[m]; }
#pragma unroll
      for (int ni = 0; ni < 4; ++ni) {
        int n = nb + wc * 64 + ni * 16 + lrow;
        float v = acc[mi][ni][r] + bias[n];
        if constexpr (MODE == 0) {
          out_f32[(size_t)m * 1024 + n] = v;
        } else if constexpr (MODE == 2) {
          float r2 = out_f32[(size_t)m * 256 + n] + v;
          out_f32[(size_t)m * 256 + n] = r2;
          out_bf16[(size_t)m * 256 + n] = f2bf(r2);
        } else {
          v += mask_emb[mk * 256 + n];
          out_f32[(size_t)m * 256 + n] = v;
          out_bf16[(size_t)m * 256 + n] = f2bf(v);
        }
      }
    }
  }
}

// ---------------------------------------------------------------------------
// Fused layer-edge kernel: e_new = e_bf@C_w + C_b + Ah[col] + Bh[row] kept in
// LDS (f32, 128x256 = 128KB); then (a) node update for the block's 8 nodes,
// (b) double-LN+silu chain -> bout bf16. BM=128, BN=256, 8 waves.
// ---------------------------------------------------------------------------
__global__ __launch_bounds__(512) void k_layer_edge(const unsigned short* __restrict__ A,
                                                    const unsigned short* __restrict__ WT,
                                                    const float* __restrict__ Cb,
                                                    const int* __restrict__ ei_col,
                                                    const float* __restrict__ XW,
                                                    const float* __restrict__ nhg, const float* __restrict__ nhb,
                                                    const float* __restrict__ neg_, const float* __restrict__ neb_,
                                                    const float* __restrict__ tvec_l,
                                                    const float* __restrict__ pg_, const float* __restrict__ pb_,
                                                    float* __restrict__ x, unsigned short* __restrict__ xb,
                                                    unsigned short* __restrict__ bout) {
  const int t = threadIdx.x;
  const int m0 = blockIdx.x * 128;
  const int lane = t & 63;
  const int wave = t >> 6;
  const int wr = wave >> 2, wc = wave & 3;  // 2 x 4 wave grid
  const int lrow = lane & 15, lg = lane >> 4;

  __shared__ __align__(16) char lds[131072];
  char* Als = lds;           // [128][128B] swizzled (during main loop)
  char* Bls = lds + 16384;   // [256][128B] swizzled
  float* enew = (float*)lds; // [128][256] f32 (after main loop)

  f32x4 acc[4][4];
#pragma unroll
  for (int i = 0; i < 4; ++i)
#pragma unroll
    for (int j = 0; j < 4; ++j) acc[i][j] = (f32x4)0.0f;

  const int wave_off = (t & 0x1C0) * 16;  // wave-uniform LDS chunk base
  for (int kt = 0; kt < 4; ++kt) {
    const int k0b = kt * 128;
#pragma unroll
    for (int c = 0; c < 2; ++c) {  // A: 128 rows
      int o = c * 8192 + t * 16;
      int row = o >> 7;
      int cb = o & 127;
      int cbl = cb ^ ((row & 7) << 4);
      gload16((const char*)A + (size_t)(m0 + row) * 512 + k0b + cbl,
              Als + c * 8192 + wave_off);
    }
#pragma unroll
    for (int c = 0; c < 4; ++c) {  // B: 256 rows (full weight)
      int o = c * 8192 + t * 16;
      int row = o >> 7;
      int cb = o & 127;
      int cbl = cb ^ ((row & 7) << 4);
      gload16((const char*)WT + (size_t)row * 512 + k0b + cbl,
              Bls + c * 8192 + wave_off);
    }
    __syncthreads();
#pragma unroll
    for (int ks = 0; ks < 2; ++ks) {
      bf16x8 af[4], bfv[4];
#pragma unroll
      for (int mi = 0; mi < 4; ++mi) {
        int ra = wr * 64 + mi * 16 + lrow;
        int cba = (ks * 64 + lg * 16) ^ ((ra & 7) << 4);
        af[mi] = *(const bf16x8*)(Als + ra * 128 + cba);
        int rb = wc * 64 + mi * 16 + lrow;
        int cbb = (ks * 64 + lg * 16) ^ ((rb & 7) << 4);
        bfv[mi] = *(const bf16x8*)(Bls + rb * 128 + cbb);
      }
#pragma unroll
      for (int mi = 0; mi < 4; ++mi)
#pragma unroll
        for (int ni = 0; ni < 4; ++ni)
          acc[mi][ni] = __builtin_amdgcn_mfma_f32_16x16x32_bf16(af[mi], bfv[ni], acc[mi][ni], 0, 0, 0);
    }
    __syncthreads();
  }

  // ---- E0: e_new -> LDS (f32), fused bias + Ah[col] + Bh[node] ----
  float bs[4];
#pragma unroll
  for (int ni = 0; ni < 4; ++ni) bs[ni] = Cb[wc * 64 + ni * 16 + lrow];
#pragma unroll
  for (int mi = 0; mi < 4; ++mi) {
#pragma unroll
    for (int r = 0; r < 4; ++r) {
      int ml = wr * 64 + mi * 16 + lg * 4 + r;
      int m = m0 + ml;
      int cv = ei_col[m];
      const float* AhR = XW + (size_t)cv * 1024 + 512;
      const float* BhR = XW + (size_t)(m >> 4) * 1024 + 768;
#pragma unroll
      for (int ni = 0; ni < 4; ++ni) {
        int n = wc * 64 + ni * 16 + lrow;
        enew[ml * 256 + n] = acc[mi][ni][r] + bs[ni] + AhR[n] + BhR[n];
      }
    }
  }
  __syncthreads();

  const int c0 = lane * 4;

  // ---- E1: node update (wave w owns node m0/16 + w) ----
  {
    int v = (m0 >> 4) + wave;
    f32x4 agg = (f32x4)0.0f;
#pragma unroll 4
    for (int k = 0; k < K_DEG; ++k) {
      f32x4 en = *(const f32x4*)&enew[(wave * 16 + k) * 256 + c0];
      int cv = ei_col[m0 + wave * 16 + k];
      f32x4 vh = *(const f32x4*)&XW[(size_t)cv * 1024 + 256 + c0];
#pragma unroll
      for (int i = 0; i < 4; ++i) agg[i] += vh[i] / (1.0f + expf(-en[i]));
    }
    f32x4 s4 = *(const f32x4*)&XW[(size_t)v * 1024 + c0];  // Uh
    s4 += agg;
    float s = s4[0] + s4[1] + s4[2] + s4[3];
    float sq = s4[0] * s4[0] + s4[1] * s4[1] + s4[2] * s4[2] + s4[3] * s4[3];
#pragma unroll
    for (int st = 1; st < 64; st <<= 1) { s += __shfl_xor(s, st); sq += __shfl_xor(sq, st); }
    float mean = s * (1.0f / H);
    float inv = rsqrtf(sq * (1.0f / H) - mean * mean + 1e-5f);
    f32x4 g = *(const f32x4*)&nhg[c0];
    f32x4 bb = *(const f32x4*)&nhb[c0];
    f32x4 xo = *(const f32x4*)&x[(size_t)v * H + c0];
    u16x4 ov;
#pragma unroll
    for (int i = 0; i < 4; ++i) {
      float h = fmaxf((s4[i] - mean) * inv * g[i] + bb[i], 0.0f);
      xo[i] += h;
      ov[i] = f2bf(xo[i]);
    }
    *(f32x4*)&x[(size_t)v * H + c0] = xo;
    *(u16x4*)&xb[(size_t)v * H + c0] = ov;
  }

  // ---- E2: edge double-LN + silu chain -> bout bf16 (wave w: rows w*16..+15) ----
  {
    f32x4 g1 = *(const f32x4*)&neg_[c0];
    f32x4 b1 = *(const f32x4*)&neb_[c0];
    f32x4 tv = *(const f32x4*)&tvec_l[c0];
    f32x4 g2 = *(const f32x4*)&pg_[c0];
    f32x4 b2 = *(const f32x4*)&pb_[c0];
    for (int k = 0; k < 16; ++k) {
      int row = wave * 16 + k;
      f32x4 vv = *(const f32x4*)&enew[row * 256 + c0];
      float s = vv[0] + vv[1] + vv[2] + vv[3];
      float sq = vv[0] * vv[0] + vv[1] * vv[1] + vv[2] * vv[2] + vv[3] * vv[3];
#pragma unroll
      for (int st = 1; st < 64; st <<= 1) { s += __shfl_xor(s, st); sq += __shfl_xor(sq, st); }
      float mean = s * (1.0f / H);
      float inv = rsqrtf(sq * (1.0f / H) - mean * mean + 1e-5f);
      f32x4 a;
#pragma unroll
      for (int i = 0; i < 4; ++i) a[i] = fmaxf((vv[i] - mean) * inv * g1[i] + b1[i], 0.0f) + tv[i];
      s = a[0] + a[1] + a[2] + a[3];
      sq = a[0] * a[0] + a[1] * a[1] + a[2] * a[2] + a[3] * a[3];
#pragma unroll
      for (int st = 1; st < 64; st <<= 1) { s += __shfl_xor(s, st); sq += __shfl_xor(sq, st); }
      mean = s * (1.0f / H);
      inv = rsqrtf(sq * (1.0f / H) - mean * mean + 1e-5f);
      u16x4 ov;
#pragma unroll
      for (int i = 0; i < 4; ++i) {
        float n = (a[i] - mean) * inv * g2[i] + b2[i];
        ov[i] = f2bf(n / (1.0f + expf(-n)));
      }
      *(u16x4*)&bout[(size_t)(m0 + row) * H + c0] = ov;
    }
  }
}

// ---------------------------------------------------------------------------
// Node positional embedding + node_w matmul
// ---------------------------------------------------------------------------
__global__ __launch_bounds__(256) void k_node_embed(const float* __restrict__ coords,
                                                    const float* __restrict__ W,
                                                    const float* __restrict__ b,
                                                    float* __restrict__ x,
                                                    unsigned short* __restrict__ xb) {
  int v = blockIdx.x;
  int j = threadIdx.x;
  __shared__ float4 pe4[H / 4];
  float cy = coords[v * 2 + 0] * 6.283185307179586f;
  float cx = coords[v * 2 + 1] * 6.283185307179586f;
  int idx = j & 127;
  float coord = (j < 128) ? cy : cx;
  float dim_t = powf(10000.0f, (2.0f * (float)(idx >> 1)) / 128.0f);
  float val = coord / dim_t;
  ((float*)pe4)[j] = (idx & 1) ? cosf(val) : sinf(val);
  __syncthreads();
  float acc = b[j];
  for (int k4 = 0; k4 < H / 4; ++k4) {
    float4 p = pe4[k4];
    int k = 4 * k4;
    acc += p.x * W[(k + 0) * H + j] + p.y * W[(k + 1) * H + j] +
           p.z * W[(k + 2) * H + j] + p.w * W[(k + 3) * H + j];
  }
  x[(size_t)v * H + j] = acc;
  xb[(size_t)v * H + j] = f2bf(acc);
}

// ---------------------------------------------------------------------------
// Edge scalar sine embedding -> pe bf16
// ---------------------------------------------------------------------------
__global__ __launch_bounds__(256) void k_pe(const float* __restrict__ e_vals, unsigned short* __restrict__ pe) {
  int eid = blockIdx.x * 4 + (threadIdx.x >> 6);
  int lane = threadIdx.x & 63;
  int c0 = lane * 4;
  float val = e_vals[eid];
  const float lg = 13.287712379549449f / 256.0f;
  u16x4 ov;
#pragma unroll
  for (int i = 0; i < 4; ++i) {
    int c = c0 + i;
    float invd = exp2f(-(float)(c & ~1) * lg);
    float arg = val * invd;
    float s = (c & 1) ? cosf(arg) : sinf(arg);
    ov[i] = f2bf(s);
  }
  *(u16x4*)&pe[(size_t)eid * H + c0] = ov;
}

// ---------------------------------------------------------------------------
// Timestep embedding MLP + per-layer conditioning
// ---------------------------------------------------------------------------
__global__ __launch_bounds__(256) void k_temb(const int* __restrict__ t,
                                              const float* __restrict__ te1_w, const float* __restrict__ te1_b,
                                              const float* __restrict__ te2_w, const float* __restrict__ te2_b,
                                              float* __restrict__ temb_out) {
  __shared__ float emb[H];
  __shared__ float h1[TE];
  int j = threadIdx.x;
  float tv = (float)t[0];
  {
    int i = j & 127;
    float f = expf(-logf(10000.0f) * (float)i / 128.0f);
    float arg = tv * f;
    emb[j] = (j < 128) ? cosf(arg) : sinf(arg);
  }
  __syncthreads();
  if (j < TE) {
    float acc = te1_b[j];
    for (int k = 0; k < H; ++k) acc += emb[k] * te1_w[k * TE + j];
    h1[j] = fmaxf(acc, 0.0f);
  }
  __syncthreads();
  if (j < TE) {
    float acc = te2_b[j];
    for (int k = 0; k < TE; ++k) acc += h1[k] * te2_w[k * TE + j];
    temb_out[j] = acc;
  }
}

__global__ __launch_bounds__(256) void k_tvec(const float* __restrict__ temb,
                                              const float* __restrict__ tl_w, const float* __restrict__ tl_b,
                                              float* __restrict__ tvec) {
  int l = blockIdx.x;
  int j = threadIdx.x;
  __shared__ float rt[TE];
  if (j < TE) rt[j] = fmaxf(temb[j], 0.0f);
  __syncthreads();
  float acc = tl_b[l * H + j];
  for (int k = 0; k < TE; ++k) acc += rt[k] * tl_w[(size_t)(l * TE + k) * H + j];
  tvec[l * H + j] = acc;
}

// ---------------------------------------------------------------------------
// GroupNorm stats (vectorized, 512 blocks x 4 waves, f64 register accum)
// ---------------------------------------------------------------------------
__global__ __launch_bounds__(256) void k_gn_stats(const float* __restrict__ e, double* __restrict__ sums) {
  int w = threadIdx.x >> 6, lane = threadIdx.x & 63;
  int c0 = lane * 4;
  double s0 = 0, s1 = 0, s2 = 0, s3 = 0, q0 = 0, q1 = 0, q2 = 0, q3 = 0;
  for (int row = blockIdx.x * 4 + w; row < E_EDGES; row += 2048) {
    f32x4 v = *(const f32x4*)&e[(size_t)row * H + c0];
    s0 += v[0]; q0 += (double)v[0] * v[0];
    s1 += v[1]; q1 += (double)v[1] * v[1];
    s2 += v[2]; q2 += (double)v[2] * v[2];
    s3 += v[3]; q3 += (double)v[3] * v[3];
  }
  __shared__ double red[2][4][H];
  red[0][w][c0 + 0] = s0; red[0][w][c0 + 1] = s1; red[0][w][c0 + 2] = s2; red[0][w][c0 + 3] = s3;
  red[1][w][c0 + 0] = q0; red[1][w][c0 + 1] = q1; red[1][w][c0 + 2] = q2; red[1][w][c0 + 3] = q3;
  __syncthreads();
  int c = threadIdx.x;
  double ts = red[0][0][c] + red[0][1][c] + red[0][2][c] + red[0][3][c];
  double tq = red[1][0][c] + red[1][1][c] + red[1][2][c] + red[1][3][c];
  atomicAdd(&sums[c], ts);
  atomicAdd(&sums[H + c], tq);
}

__global__ void k_gn_finalize(const double* __restrict__ sums, float* __restrict__ gstats) {
  int g = threadIdx.x;
  if (g < 32) {
    double s = 0.0, sq = 0.0;
    for (int c = g * 8; c < g * 8 + 8; ++c) {
      s += sums[c];
      sq += sums[H + c];
    }
    double n = 8.0 * (double)E_EDGES;
    double mean = s / n;
    double var = sq / n - mean * mean;
    gstats[g] = (float)mean;
    gstats[32 + g] = (float)(1.0 / sqrt(var + 1e-5));
  }
}

__global__ __launch_bounds__(256) void k_head(const float* __restrict__ e,
                                              const float* __restrict__ gstats,
                                              const float* __restrict__ gn_g, const float* __restrict__ gn_b,
                                              const float* __restrict__ out_w, const float* __restrict__ out_b,
                                              float* __restrict__ out) {
  int wv = threadIdx.x >> 6;
  int lane = threadIdx.x & 63;
  int eid = blockIdx.x * 4 + wv;
  int c0 = lane * 4;
  float4 ev = *(const float4*)&e[(size_t)eid * H + c0];
  float vv[4] = {ev.x, ev.y, ev.z, ev.w};
  float a0 = 0.0f, a1 = 0.0f;
#pragma unroll
  for (int i = 0; i < 4; ++i) {
    int c = c0 + i;
    int g = c >> 3;
    float v = (vv[i] - gstats[g]) * gstats[32 + g] * gn_g[c] + gn_b[c];
    v = fmaxf(v, 0.0f);
    a0 += v * out_w[c * 2 + 0];
    a1 += v * out_w[c * 2 + 1];
  }
  for (int s = 32; s > 0; s >>= 1) {
    a0 += __shfl_down(a0, s);
    a1 += __shfl_down(a1, s);
  }
  if (lane == 0) {
    out[(size_t)eid * 2 + 0] = a0 + out_b[0];
    out[(size_t)eid * 2 + 1] = a1 + out_b[1];
  }
}

// ---------------------------------------------------------------------------
extern "C" void kernel_launch(void* const* d_in, const int* in_sizes, int n_in,
                              void* d_out, int out_size, void* d_ws, size_t ws_size,
                              hipStream_t stream) {
  const float* nodes_feature = (const float*)d_in[0];
  const float* e_vals = (const float*)d_in[1];
  const int* mask = (const int*)d_in[2];
  const int* t = (const int*)d_in[3];
  const int* edge_index = (const int*)d_in[4];
  const float* node_w = (const float*)d_in[5];
  const float* node_b = (const float*)d_in[6];
  const float* edge_w = (const float*)d_in[7];
  const float* edge_b = (const float*)d_in[8];
  const float* te1_w = (const float*)d_in[9];
  const float* te1_b = (const float*)d_in[10];
  const float* te2_w = (const float*)d_in[11];
  const float* te2_b = (const float*)d_in[12];
  const float* U_w = (const float*)d_in[13];
  const float* U_b = (const float*)d_in[14];
  const float* V_w = (const float*)d_in[15];
  const float* V_b = (const float*)d_in[16];
  const float* A_w = (const float*)d_in[17];
  const float* A_b = (const float*)d_in[18];
  const float* B_w = (const float*)d_in[19];
  const float* B_b = (const float*)d_in[20];
  const float* C_w = (const float*)d_in[21];
  const float* C_b = (const float*)d_in[22];
  const float* nh_g = (const float*)d_in[23];
  const float* nh_b = (const float*)d_in[24];
  const float* ne_g = (const float*)d_in[25];
  const float* ne_b = (const float*)d_in[26];
  const float* tl_w = (const float*)d_in[27];
  const float* tl_b = (const float*)d_in[28];
  const float* plo_g = (const float*)d_in[29];
  const float* plo_b = (const float*)d_in[30];
  const float* plo_w = (const float*)d_in[31];
  const float* plo_b2 = (const float*)d_in[32];
  const float* gn_g = (const float*)d_in[33];
  const float* gn_b = (const float*)d_in[34];
  const float* out_w = (const float*)d_in[35];
  const float* out_b = (const float*)d_in[36];
  const float* mask_emb = (const float*)d_in[37];

  char* wsb = (char*)d_ws;
  size_t off = 0;
  auto alloc = [&](size_t bytes) -> void* {
    void* p = wsb + off;
    off += (bytes + 255) & ~(size_t)255;
    return p;
  };
  double* gn_sums = (double*)alloc(512 * sizeof(double));
  float* XW = (float*)alloc((size_t)V_NODES * 1024 * 4);
  float* e = (float*)alloc((size_t)E_EDGES * H * 4);
  unsigned short* e_bf = (unsigned short*)alloc((size_t)E_EDGES * H * 2);
  unsigned short* pe_b = (unsigned short*)alloc((size_t)E_EDGES * H * 2);  // pe, reused as b
  unsigned short* x_bf = (unsigned short*)alloc((size_t)V_NODES * H * 2);
  unsigned short* WT4 = (unsigned short*)alloc((size_t)L_LAYERS * 1024 * H * 2);
  unsigned short* WTC = (unsigned short*)alloc((size_t)L_LAYERS * H * H * 2);
  unsigned short* WTplo = (unsigned short*)alloc((size_t)L_LAYERS * H * H * 2);
  unsigned short* WTedge = (unsigned short*)alloc((size_t)H * H * 2);
  float* b4 = (float*)alloc((size_t)L_LAYERS * 1024 * 4);
  float* temb = (float*)alloc(TE * 4);
  float* tvec = (float*)alloc((size_t)L_LAYERS * H * 4);
  float* gstats = (float*)alloc(64 * 4);

  const int* ei_col = edge_index + E_EDGES;

  float* x = (float*)d_out;
  float* out2 = (float*)d_out + (size_t)V_NODES * H;

  k_prep_w<<<1168, 256, 0, stream>>>(U_w, V_w, A_w, B_w, C_w, plo_w, edge_w, WT4, WTC, WTplo, WTedge);
  k_prep_b<<<L_LAYERS, 256, 0, stream>>>(U_b, V_b, A_b, B_b, b4);
  k_node_embed<<<V_NODES, 256, 0, stream>>>(nodes_feature, node_w, node_b, x, x_bf);
  k_pe<<<E_EDGES / 4, 256, 0, stream>>>(e_vals, pe_b);
  k_temb<<<1, 256, 0, stream>>>(t, te1_w, te1_b, te2_w, te2_b, temb);
  k_tvec<<<L_LAYERS, 256, 0, stream>>>(temb, tl_w, tl_b, tvec);
  k_gemm<3><<<dim3(E_EDGES / 128, 2), 256, 0, stream>>>(pe_b, WTedge, E_EDGES, edge_b, mask, mask_emb, e, e_bf);

  for (int l = 0; l < L_LAYERS; ++l) {
    size_t wo = (size_t)l * H * H;
    size_t bo = (size_t)l * H;
    k_gemm<0><<<dim3(24, 8), 256, 0, stream>>>(x_bf, WT4 + (size_t)l * 1024 * H, V_NODES, b4 + l * 1024,
                                               nullptr, nullptr, XW, nullptr);
    k_layer_edge<<<E_EDGES / 128, 512, 0, stream>>>(e_bf, WTC + wo, C_b + bo, ei_col, XW,
                                                    nh_g + bo, nh_b + bo, ne_g + bo, ne_b + bo, tvec + bo,
                                                    plo_g + bo, plo_b + bo, x, x_bf, pe_b);
    k_gemm<2><<<dim3(E_EDGES / 128, 2), 256, 0, stream>>>(pe_b, WTplo + wo, E_EDGES, plo_b2 + bo,
                                                          nullptr, nullptr, e, e_bf);
  }

  hipMemsetAsync(gn_sums, 0, 512 * sizeof(double), stream);
  k_gn_stats<<<512, 256, 0, stream>>>(e, gn_sums);
  k_gn_finalize<<<1, 64, 0, stream>>>(gn_sums, gstats);
  k_head<<<E_EDGES / 4, 256, 0, stream>>>(e, gstats, gn_g, gn_b, out_w, out_b, out2);
}

// Round 4
// 1142.801 us; speedup vs baseline: 4.9307x; 1.2445x over previous
//
#include <hip/hip_runtime.h>
#include <math.h>

#define V_NODES 3000
#define K_DEG 16
#define E_EDGES 48000
#define H 256
#define TE 128
#define L_LAYERS 12

typedef __attribute__((ext_vector_type(4))) float f32x4;
typedef __attribute__((ext_vector_type(8))) __bf16 bf16x8;
typedef __attribute__((ext_vector_type(4))) unsigned short u16x4;

__device__ __forceinline__ unsigned short f2bf(float f) {
  unsigned u = __float_as_uint(f);
  unsigned r = (u + 0x7fffu + ((u >> 16) & 1u)) >> 16;
  return (unsigned short)r;
}

__device__ __forceinline__ void gload16(const void* g, void* l) {
  __builtin_amdgcn_global_load_lds((const __attribute__((address_space(1))) void*)g,
                                   (__attribute__((address_space(3))) void*)l, 16, 0, 0);
}

// ---------------------------------------------------------------------------
// Weight prep: transpose 256x256 f32 [k][n] -> bf16 [n][k]; UVAB packed to
// [1024][256] per layer.
// ---------------------------------------------------------------------------
__global__ __launch_bounds__(256) void k_prep_w(const float* __restrict__ U_w, const float* __restrict__ V_w,
                                                const float* __restrict__ A_w, const float* __restrict__ B_w,
                                                const float* __restrict__ C_w, const float* __restrict__ plo_w,
                                                const float* __restrict__ edge_w,
                                                unsigned short* __restrict__ WT4, unsigned short* __restrict__ WTC,
                                                unsigned short* __restrict__ WTplo, unsigned short* __restrict__ WTedge) {
  int bid = blockIdx.x;
  const float* src;
  unsigned short* dst;
  int tt;
  if (bid < 768) {
    int l = bid >> 6;
    int rem = bid & 63;
    int mat = rem >> 4;
    tt = rem & 15;
    const float* srcs[4] = {U_w, V_w, A_w, B_w};
    src = srcs[mat] + (size_t)l * H * H;
    dst = WT4 + (size_t)l * 1024 * H + (size_t)mat * H * H;
  } else if (bid < 960) {
    int b2 = bid - 768;
    int l = b2 >> 4;
    tt = b2 & 15;
    src = C_w + (size_t)l * H * H;
    dst = WTC + (size_t)l * H * H;
  } else if (bid < 1152) {
    int b2 = bid - 960;
    int l = b2 >> 4;
    tt = b2 & 15;
    src = plo_w + (size_t)l * H * H;
    dst = WTplo + (size_t)l * H * H;
  } else {
    tt = bid - 1152;
    src = edge_w;
    dst = WTedge;
  }
  int k0 = (tt & 3) * 64, n0 = (tt >> 2) * 64;
  __shared__ float ts[64][65];
  int c = threadIdx.x & 63;
  int r0 = threadIdx.x >> 6;
  for (int rr = 0; rr < 64; rr += 4) {
    int r = rr + r0;
    ts[r][c] = src[(size_t)(k0 + r) * H + n0 + c];
  }
  __syncthreads();
  for (int nn = 0; nn < 64; nn += 4) {
    int n = nn + r0;
    dst[(size_t)(n0 + n) * H + k0 + c] = f2bf(ts[c][n]);
  }
}

__global__ __launch_bounds__(256) void k_prep_b(const float* __restrict__ U_b, const float* __restrict__ V_b,
                                                const float* __restrict__ A_b, const float* __restrict__ B_b,
                                                float* __restrict__ b4) {
  int l = blockIdx.x;
  int t = threadIdx.x;
  b4[l * 1024 + 0 + t] = U_b[l * H + t];
  b4[l * 1024 + 256 + t] = V_b[l * H + t];
  b4[l * 1024 + 512 + t] = A_b[l * H + t];
  b4[l * 1024 + 768 + t] = B_b[l * H + t];
}

// ---------------------------------------------------------------------------
// Plain MFMA GEMM (128x128 tile, 4 waves, BK=64) for node-UVAB / plo / embed.
// MODE 0: node UVAB   -> out_f32[m*1024+n] = acc + bias[n]
// MODE 2: edge plo    -> e += acc + bias; write e f32 + e bf16
// MODE 3: edge embed  -> acc + bias + mask_emb[mask[m]]; write e f32 + bf16
// ---------------------------------------------------------------------------
template <int MODE>
__global__ __launch_bounds__(256) void k_gemm(const unsigned short* __restrict__ A,
                                              const unsigned short* __restrict__ WT,
                                              int M,
                                              const float* __restrict__ bias,
                                              const int* __restrict__ maskp,
                                              const float* __restrict__ mask_emb,
                                              float* __restrict__ out_f32,
                                              unsigned short* __restrict__ out_bf16) {
  const int t = threadIdx.x;
  const int m0 = blockIdx.x * 128;
  const int nb = blockIdx.y * 128;
  const int lane = t & 63;
  const int wave = t >> 6;
  const int wr = wave >> 1, wc = wave & 1;
  const int lrow = lane & 15, lg = lane >> 4;

  __shared__ __align__(16) char lds[32768];
  char* Als = lds;
  char* Bls = lds + 16384;

  f32x4 acc[4][4];
#pragma unroll
  for (int i = 0; i < 4; ++i)
#pragma unroll
    for (int j = 0; j < 4; ++j) acc[i][j] = (f32x4)0.0f;

  for (int kt = 0; kt < 4; ++kt) {
    const int k0b = kt * 128;
#pragma unroll
    for (int i = 0; i < 4; ++i) {
      int o = i * 4096 + t * 16;
      int row = o >> 7;
      int cb = o & 127;
      int cbl = cb ^ ((row & 7) << 4);
      int rA = m0 + row;
      rA = rA < M ? rA : 0;
      gload16((const char*)A + (size_t)rA * 512 + k0b + cbl,
              Als + i * 4096 + (t & 192) * 16);
      gload16((const char*)WT + (size_t)(nb + row) * 512 + k0b + cbl,
              Bls + i * 4096 + (t & 192) * 16);
    }
    __syncthreads();
#pragma unroll
    for (int ks = 0; ks < 2; ++ks) {
      bf16x8 af[4], bfv[4];
#pragma unroll
      for (int mi = 0; mi < 4; ++mi) {
        int ra = wr * 64 + mi * 16 + lrow;
        int cba = (ks * 64 + lg * 16) ^ ((ra & 7) << 4);
        af[mi] = *(const bf16x8*)(Als + ra * 128 + cba);
        int rb = wc * 64 + mi * 16 + lrow;
        int cbb = (ks * 64 + lg * 16) ^ ((rb & 7) << 4);
        bfv[mi] = *(const bf16x8*)(Bls + rb * 128 + cbb);
      }
#pragma unroll
      for (int mi = 0; mi < 4; ++mi)
#pragma unroll
        for (int ni = 0; ni < 4; ++ni)
          acc[mi][ni] = __builtin_amdgcn_mfma_f32_16x16x32_bf16(af[mi], bfv[ni], acc[mi][ni], 0, 0, 0);
    }
    __syncthreads();
  }

#pragma unroll
  for (int mi = 0; mi < 4; ++mi) {
#pragma unroll
    for (int r = 0; r < 4; ++r) {
      int m = m0 + wr * 64 + mi * 16 + lg * 4 + r;
      if (MODE == 0 && m >= M) continue;
      int mk = 0;
      if constexpr (MODE == 3) { mk = maskp[m]; }
#pragma unroll
      for (int ni = 0; ni < 4; ++ni) {
        int n = nb + wc * 64 + ni * 16 + lrow;
        float v = acc[mi][ni][r] + bias[n];
        if constexpr (MODE == 0) {
          out_f32[(size_t)m * 1024 + n] = v;
        } else if constexpr (MODE == 2) {
          float r2 = out_f32[(size_t)m * 256 + n] + v;
          out_f32[(size_t)m * 256 + n] = r2;
          out_bf16[(size_t)m * 256 + n] = f2bf(r2);
        } else {
          v += mask_emb[mk * 256 + n];
          out_f32[(size_t)m * 256 + n] = v;
          out_bf16[(size_t)m * 256 + n] = f2bf(v);
        }
      }
    }
  }
}

// ---------------------------------------------------------------------------
// Fused layer-edge kernel v2: BM=64 (4 nodes), BN=256, 8 waves (512 thr).
// LDS = max(A 8K + B 32K, enew 64x256 f32) = 64KB -> 2 blocks/CU.
// enew stored XOR-swizzled: f32 index n ^= (row&15)<<2 (16B-granular involution).
// Epilogue: waves 0-3 node-update + 6 LN rows; waves 4-7 10 LN rows each.
// ---------------------------------------------------------------------------
__global__ __launch_bounds__(512) void k_layer_edge(const unsigned short* __restrict__ A,
                                                    const unsigned short* __restrict__ WT,
                                                    const float* __restrict__ Cb,
                                                    const int* __restrict__ ei_col,
                                                    const float* __restrict__ XW,
                                                    const float* __restrict__ nhg, const float* __restrict__ nhb,
                                                    const float* __restrict__ neg_, const float* __restrict__ neb_,
                                                    const float* __restrict__ tvec_l,
                                                    const float* __restrict__ pg_, const float* __restrict__ pb_,
                                                    float* __restrict__ x, unsigned short* __restrict__ xb,
                                                    unsigned short* __restrict__ bout) {
  const int t = threadIdx.x;
  const int m0 = blockIdx.x * 64;
  const int lane = t & 63;
  const int wave = t >> 6;
  const int wr = wave >> 2, wc = wave & 3;  // 2 x 4 wave grid: 32 rows x 64 cols each
  const int lrow = lane & 15, lg = lane >> 4;

  __shared__ __align__(16) char lds[65536];
  char* Als = lds;            // [64][128B] swizzled (GEMM phase)
  char* Bls = lds + 8192;     // [256][128B] swizzled (GEMM phase)
  float* enew = (float*)lds;  // [64][256] f32 swizzled (epilogue phase)

  f32x4 acc[2][4];
#pragma unroll
  for (int i = 0; i < 2; ++i)
#pragma unroll
    for (int j = 0; j < 4; ++j) acc[i][j] = (f32x4)0.0f;

  const int wave_off = wave * 1024;  // wave-uniform LDS chunk base
  for (int kt = 0; kt < 4; ++kt) {
    const int k0b = kt * 128;
    {  // A: 64 rows x 128B = 8KB, one 16B load per thread
      int o = t * 16;
      int row = o >> 7;
      int cb = o & 127;
      int cbl = cb ^ ((row & 7) << 4);
      gload16((const char*)A + (size_t)(m0 + row) * 512 + k0b + cbl, Als + wave_off);
    }
#pragma unroll
    for (int c = 0; c < 4; ++c) {  // B: 256 rows (full weight), 32KB
      int o = c * 8192 + t * 16;
      int row = o >> 7;
      int cb = o & 127;
      int cbl = cb ^ ((row & 7) << 4);
      gload16((const char*)WT + (size_t)row * 512 + k0b + cbl,
              Bls + c * 8192 + wave_off);
    }
    __syncthreads();
#pragma unroll
    for (int ks = 0; ks < 2; ++ks) {
      bf16x8 af[2], bfv[4];
#pragma unroll
      for (int mi = 0; mi < 2; ++mi) {
        int ra = wr * 32 + mi * 16 + lrow;
        int cba = (ks * 64 + lg * 16) ^ ((ra & 7) << 4);
        af[mi] = *(const bf16x8*)(Als + ra * 128 + cba);
      }
#pragma unroll
      for (int ni = 0; ni < 4; ++ni) {
        int rb = wc * 64 + ni * 16 + lrow;
        int cbb = (ks * 64 + lg * 16) ^ ((rb & 7) << 4);
        bfv[ni] = *(const bf16x8*)(Bls + rb * 128 + cbb);
      }
#pragma unroll
      for (int mi = 0; mi < 2; ++mi)
#pragma unroll
        for (int ni = 0; ni < 4; ++ni)
          acc[mi][ni] = __builtin_amdgcn_mfma_f32_16x16x32_bf16(af[mi], bfv[ni], acc[mi][ni], 0, 0, 0);
    }
    __syncthreads();
  }

  // ---- E0: e_new -> LDS (f32, swizzled), fused bias + Ah[col] + Bh[node] ----
  float bs[4];
#pragma unroll
  for (int ni = 0; ni < 4; ++ni) bs[ni] = Cb[wc * 64 + ni * 16 + lrow];
#pragma unroll
  for (int mi = 0; mi < 2; ++mi) {
#pragma unroll
    for (int r = 0; r < 4; ++r) {
      int ml = wr * 32 + mi * 16 + lg * 4 + r;
      int m = m0 + ml;
      int cv = ei_col[m];
      const float* AhR = XW + (size_t)cv * 1024 + 512;
      const float* BhR = XW + (size_t)(m >> 4) * 1024 + 768;
      int sw = (ml & 15) << 2;
#pragma unroll
      for (int ni = 0; ni < 4; ++ni) {
        int n = wc * 64 + ni * 16 + lrow;
        enew[ml * 256 + (n ^ sw)] = acc[mi][ni][r] + bs[ni] + AhR[n] + BhR[n];
      }
    }
  }
  __syncthreads();

  const int c0 = lane * 4;

  // ---- E1: node update (waves 0-3, one node each) ----
  if (wave < 4) {
    int v = (m0 >> 4) + wave;
    f32x4 agg = (f32x4)0.0f;
#pragma unroll 4
    for (int k = 0; k < K_DEG; ++k) {
      int row = wave * 16 + k;
      f32x4 en = *(const f32x4*)&enew[row * 256 + (c0 ^ ((row & 15) << 2))];
      int cv = ei_col[m0 + row];
      f32x4 vh = *(const f32x4*)&XW[(size_t)cv * 1024 + 256 + c0];
#pragma unroll
      for (int i = 0; i < 4; ++i) agg[i] += vh[i] / (1.0f + expf(-en[i]));
    }
    f32x4 s4 = *(const f32x4*)&XW[(size_t)v * 1024 + c0];  // Uh
    s4 += agg;
    float s = s4[0] + s4[1] + s4[2] + s4[3];
    float sq = s4[0] * s4[0] + s4[1] * s4[1] + s4[2] * s4[2] + s4[3] * s4[3];
#pragma unroll
    for (int st = 1; st < 64; st <<= 1) { s += __shfl_xor(s, st); sq += __shfl_xor(sq, st); }
    float mean = s * (1.0f / H);
    float inv = rsqrtf(sq * (1.0f / H) - mean * mean + 1e-5f);
    f32x4 g = *(const f32x4*)&nhg[c0];
    f32x4 bb = *(const f32x4*)&nhb[c0];
    f32x4 xo = *(const f32x4*)&x[(size_t)v * H + c0];
    u16x4 ov;
#pragma unroll
    for (int i = 0; i < 4; ++i) {
      float h = fmaxf((s4[i] - mean) * inv * g[i] + bb[i], 0.0f);
      xo[i] += h;
      ov[i] = f2bf(xo[i]);
    }
    *(f32x4*)&x[(size_t)v * H + c0] = xo;
    *(u16x4*)&xb[(size_t)v * H + c0] = ov;
  }

  // ---- E2: edge double-LN + silu chain -> bout bf16 ----
  // waves 4-7: rows 0..39 (10 each); waves 0-3: rows 40..63 (6 each)
  {
    f32x4 g1 = *(const f32x4*)&neg_[c0];
    f32x4 b1 = *(const f32x4*)&neb_[c0];
    f32x4 tv = *(const f32x4*)&tvec_l[c0];
    f32x4 g2 = *(const f32x4*)&pg_[c0];
    f32x4 b2 = *(const f32x4*)&pb_[c0];
    int nrows = (wave < 4) ? 6 : 10;
    int rbase = (wave < 4) ? 40 + wave * 6 : (wave - 4) * 10;
    for (int k = 0; k < nrows; ++k) {
      int row = rbase + k;
      f32x4 vv = *(const f32x4*)&enew[row * 256 + (c0 ^ ((row & 15) << 2))];
      float s = vv[0] + vv[1] + vv[2] + vv[3];
      float sq = vv[0] * vv[0] + vv[1] * vv[1] + vv[2] * vv[2] + vv[3] * vv[3];
#pragma unroll
      for (int st = 1; st < 64; st <<= 1) { s += __shfl_xor(s, st); sq += __shfl_xor(sq, st); }
      float mean = s * (1.0f / H);
      float inv = rsqrtf(sq * (1.0f / H) - mean * mean + 1e-5f);
      f32x4 a;
#pragma unroll
      for (int i = 0; i < 4; ++i) a[i] = fmaxf((vv[i] - mean) * inv * g1[i] + b1[i], 0.0f) + tv[i];
      s = a[0] + a[1] + a[2] + a[3];
      sq = a[0] * a[0] + a[1] * a[1] + a[2] * a[2] + a[3] * a[3];
#pragma unroll
      for (int st = 1; st < 64; st <<= 1) { s += __shfl_xor(s, st); sq += __shfl_xor(sq, st); }
      mean = s * (1.0f / H);
      inv = rsqrtf(sq * (1.0f / H) - mean * mean + 1e-5f);
      u16x4 ov;
#pragma unroll
      for (int i = 0; i < 4; ++i) {
        float n = (a[i] - mean) * inv * g2[i] + b2[i];
        ov[i] = f2bf(n / (1.0f + expf(-n)));
      }
      *(u16x4*)&bout[(size_t)(m0 + row) * H + c0] = ov;
    }
  }
}

// ---------------------------------------------------------------------------
// Node positional embedding + node_w matmul
// ---------------------------------------------------------------------------
__global__ __launch_bounds__(256) void k_node_embed(const float* __restrict__ coords,
                                                    const float* __restrict__ W,
                                                    const float* __restrict__ b,
                                                    float* __restrict__ x,
                                                    unsigned short* __restrict__ xb) {
  int v = blockIdx.x;
  int j = threadIdx.x;
  __shared__ float4 pe4[H / 4];
  float cy = coords[v * 2 + 0] * 6.283185307179586f;
  float cx = coords[v * 2 + 1] * 6.283185307179586f;
  int idx = j & 127;
  float coord = (j < 128) ? cy : cx;
  float dim_t = powf(10000.0f, (2.0f * (float)(idx >> 1)) / 128.0f);
  float val = coord / dim_t;
  ((float*)pe4)[j] = (idx & 1) ? cosf(val) : sinf(val);
  __syncthreads();
  float acc = b[j];
  for (int k4 = 0; k4 < H / 4; ++k4) {
    float4 p = pe4[k4];
    int k = 4 * k4;
    acc += p.x * W[(k + 0) * H + j] + p.y * W[(k + 1) * H + j] +
           p.z * W[(k + 2) * H + j] + p.w * W[(k + 3) * H + j];
  }
  x[(size_t)v * H + j] = acc;
  xb[(size_t)v * H + j] = f2bf(acc);
}

// ---------------------------------------------------------------------------
// Edge scalar sine embedding -> pe bf16
// ---------------------------------------------------------------------------
__global__ __launch_bounds__(256) void k_pe(const float* __restrict__ e_vals, unsigned short* __restrict__ pe) {
  int eid = blockIdx.x * 4 + (threadIdx.x >> 6);
  int lane = threadIdx.x & 63;
  int c0 = lane * 4;
  float val = e_vals[eid];
  const float lg = 13.287712379549449f / 256.0f;
  u16x4 ov;
#pragma unroll
  for (int i = 0; i < 4; ++i) {
    int c = c0 + i;
    float invd = exp2f(-(float)(c & ~1) * lg);
    float arg = val * invd;
    float s = (c & 1) ? cosf(arg) : sinf(arg);
    ov[i] = f2bf(s);
  }
  *(u16x4*)&pe[(size_t)eid * H + c0] = ov;
}

// ---------------------------------------------------------------------------
// Timestep embedding MLP + per-layer conditioning
// ---------------------------------------------------------------------------
__global__ __launch_bounds__(256) void k_temb(const int* __restrict__ t,
                                              const float* __restrict__ te1_w, const float* __restrict__ te1_b,
                                              const float* __restrict__ te2_w, const float* __restrict__ te2_b,
                                              float* __restrict__ temb_out) {
  __shared__ float emb[H];
  __shared__ float h1[TE];
  int j = threadIdx.x;
  float tv = (float)t[0];
  {
    int i = j & 127;
    float f = expf(-logf(10000.0f) * (float)i / 128.0f);
    float arg = tv * f;
    emb[j] = (j < 128) ? cosf(arg) : sinf(arg);
  }
  __syncthreads();
  if (j < TE) {
    float acc = te1_b[j];
    for (int k = 0; k < H; ++k) acc += emb[k] * te1_w[k * TE + j];
    h1[j] = fmaxf(acc, 0.0f);
  }
  __syncthreads();
  if (j < TE) {
    float acc = te2_b[j];
    for (int k = 0; k < TE; ++k) acc += h1[k] * te2_w[k * TE + j];
    temb_out[j] = acc;
  }
}

__global__ __launch_bounds__(256) void k_tvec(const float* __restrict__ temb,
                                              const float* __restrict__ tl_w, const float* __restrict__ tl_b,
                                              float* __restrict__ tvec) {
  int l = blockIdx.x;
  int j = threadIdx.x;
  __shared__ float rt[TE];
  if (j < TE) rt[j] = fmaxf(temb[j], 0.0f);
  __syncthreads();
  float acc = tl_b[l * H + j];
  for (int k = 0; k < TE; ++k) acc += rt[k] * tl_w[(size_t)(l * TE + k) * H + j];
  tvec[l * H + j] = acc;
}

// ---------------------------------------------------------------------------
// GroupNorm stats (vectorized, 512 blocks x 4 waves, f64 register accum)
// ---------------------------------------------------------------------------
__global__ __launch_bounds__(256) void k_gn_stats(const float* __restrict__ e, double* __restrict__ sums) {
  int w = threadIdx.x >> 6, lane = threadIdx.x & 63;
  int c0 = lane * 4;
  double s0 = 0, s1 = 0, s2 = 0, s3 = 0, q0 = 0, q1 = 0, q2 = 0, q3 = 0;
  for (int row = blockIdx.x * 4 + w; row < E_EDGES; row += 2048) {
    f32x4 v = *(const f32x4*)&e[(size_t)row * H + c0];
    s0 += v[0]; q0 += (double)v[0] * v[0];
    s1 += v[1]; q1 += (double)v[1] * v[1];
    s2 += v[2]; q2 += (double)v[2] * v[2];
    s3 += v[3]; q3 += (double)v[3] * v[3];
  }
  __shared__ double red[2][4][H];
  red[0][w][c0 + 0] = s0; red[0][w][c0 + 1] = s1; red[0][w][c0 + 2] = s2; red[0][w][c0 + 3] = s3;
  red[1][w][c0 + 0] = q0; red[1][w][c0 + 1] = q1; red[1][w][c0 + 2] = q2; red[1][w][c0 + 3] = q3;
  __syncthreads();
  int c = threadIdx.x;
  double ts = red[0][0][c] + red[0][1][c] + red[0][2][c] + red[0][3][c];
  double tq = red[1][0][c] + red[1][1][c] + red[1][2][c] + red[1][3][c];
  atomicAdd(&sums[c], ts);
  atomicAdd(&sums[H + c], tq);
}

__global__ void k_gn_finalize(const double* __restrict__ sums, float* __restrict__ gstats) {
  int g = threadIdx.x;
  if (g < 32) {
    double s = 0.0, sq = 0.0;
    for (int c = g * 8; c < g * 8 + 8; ++c) {
      s += sums[c];
      sq += sums[H + c];
    }
    double n = 8.0 * (double)E_EDGES;
    double mean = s / n;
    double var = sq / n - mean * mean;
    gstats[g] = (float)mean;
    gstats[32 + g] = (float)(1.0 / sqrt(var + 1e-5));
  }
}

__global__ __launch_bounds__(256) void k_head(const float* __restrict__ e,
                                              const float* __restrict__ gstats,
                                              const float* __restrict__ gn_g, const float* __restrict__ gn_b,
                                              const float* __restrict__ out_w, const float* __restrict__ out_b,
                                              float* __restrict__ out) {
  int wv = threadIdx.x >> 6;
  int lane = threadIdx.x & 63;
  int eid = blockIdx.x * 4 + wv;
  int c0 = lane * 4;
  float4 ev = *(const float4*)&e[(size_t)eid * H + c0];
  float vv[4] = {ev.x, ev.y, ev.z, ev.w};
  float a0 = 0.0f, a1 = 0.0f;
#pragma unroll
  for (int i = 0; i < 4; ++i) {
    int c = c0 + i;
    int g = c >> 3;
    float v = (vv[i] - gstats[g]) * gstats[32 + g] * gn_g[c] + gn_b[c];
    v = fmaxf(v, 0.0f);
    a0 += v * out_w[c * 2 + 0];
    a1 += v * out_w[c * 2 + 1];
  }
  for (int s = 32; s > 0; s >>= 1) {
    a0 += __shfl_down(a0, s);
    a1 += __shfl_down(a1, s);
  }
  if (lane == 0) {
    out[(size_t)eid * 2 + 0] = a0 + out_b[0];
    out[(size_t)eid * 2 + 1] = a1 + out_b[1];
  }
}

// ---------------------------------------------------------------------------
extern "C" void kernel_launch(void* const* d_in, const int* in_sizes, int n_in,
                              void* d_out, int out_size, void* d_ws, size_t ws_size,
                              hipStream_t stream) {
  const float* nodes_feature = (const float*)d_in[0];
  const float* e_vals = (const float*)d_in[1];
  const int* mask = (const int*)d_in[2];
  const int* t = (const int*)d_in[3];
  const int* edge_index = (const int*)d_in[4];
  const float* node_w = (const float*)d_in[5];
  const float* node_b = (const float*)d_in[6];
  const float* edge_w = (const float*)d_in[7];
  const float* edge_b = (const float*)d_in[8];
  const float* te1_w = (const float*)d_in[9];
  const float* te1_b = (const float*)d_in[10];
  const float* te2_w = (const float*)d_in[11];
  const float* te2_b = (const float*)d_in[12];
  const float* U_w = (const float*)d_in[13];
  const float* U_b = (const float*)d_in[14];
  const float* V_w = (const float*)d_in[15];
  const float* V_b = (const float*)d_in[16];
  const float* A_w = (const float*)d_in[17];
  const float* A_b = (const float*)d_in[18];
  const float* B_w = (const float*)d_in[19];
  const float* B_b = (const float*)d_in[20];
  const float* C_w = (const float*)d_in[21];
  const float* C_b = (const float*)d_in[22];
  const float* nh_g = (const float*)d_in[23];
  const float* nh_b = (const float*)d_in[24];
  const float* ne_g = (const float*)d_in[25];
  const float* ne_b = (const float*)d_in[26];
  const float* tl_w = (const float*)d_in[27];
  const float* tl_b = (const float*)d_in[28];
  const float* plo_g = (const float*)d_in[29];
  const float* plo_b = (const float*)d_in[30];
  const float* plo_w = (const float*)d_in[31];
  const float* plo_b2 = (const float*)d_in[32];
  const float* gn_g = (const float*)d_in[33];
  const float* gn_b = (const float*)d_in[34];
  const float* out_w = (const float*)d_in[35];
  const float* out_b = (const float*)d_in[36];
  const float* mask_emb = (const float*)d_in[37];

  char* wsb = (char*)d_ws;
  size_t off = 0;
  auto alloc = [&](size_t bytes) -> void* {
    void* p = wsb + off;
    off += (bytes + 255) & ~(size_t)255;
    return p;
  };
  double* gn_sums = (double*)alloc(512 * sizeof(double));
  float* XW = (float*)alloc((size_t)V_NODES * 1024 * 4);
  float* e = (float*)alloc((size_t)E_EDGES * H * 4);
  unsigned short* e_bf = (unsigned short*)alloc((size_t)E_EDGES * H * 2);
  unsigned short* pe_b = (unsigned short*)alloc((size_t)E_EDGES * H * 2);  // pe, reused as b
  unsigned short* x_bf = (unsigned short*)alloc((size_t)V_NODES * H * 2);
  unsigned short* WT4 = (unsigned short*)alloc((size_t)L_LAYERS * 1024 * H * 2);
  unsigned short* WTC = (unsigned short*)alloc((size_t)L_LAYERS * H * H * 2);
  unsigned short* WTplo = (unsigned short*)alloc((size_t)L_LAYERS * H * H * 2);
  unsigned short* WTedge = (unsigned short*)alloc((size_t)H * H * 2);
  float* b4 = (float*)alloc((size_t)L_LAYERS * 1024 * 4);
  float* temb = (float*)alloc(TE * 4);
  float* tvec = (float*)alloc((size_t)L_LAYERS * H * 4);
  float* gstats = (float*)alloc(64 * 4);

  const int* ei_col = edge_index + E_EDGES;

  float* x = (float*)d_out;
  float* out2 = (float*)d_out + (size_t)V_NODES * H;

  k_prep_w<<<1168, 256, 0, stream>>>(U_w, V_w, A_w, B_w, C_w, plo_w, edge_w, WT4, WTC, WTplo, WTedge);
  k_prep_b<<<L_LAYERS, 256, 0, stream>>>(U_b, V_b, A_b, B_b, b4);
  k_node_embed<<<V_NODES, 256, 0, stream>>>(nodes_feature, node_w, node_b, x, x_bf);
  k_pe<<<E_EDGES / 4, 256, 0, stream>>>(e_vals, pe_b);
  k_temb<<<1, 256, 0, stream>>>(t, te1_w, te1_b, te2_w, te2_b, temb);
  k_tvec<<<L_LAYERS, 256, 0, stream>>>(temb, tl_w, tl_b, tvec);
  k_gemm<3><<<dim3(E_EDGES / 128, 2), 256, 0, stream>>>(pe_b, WTedge, E_EDGES, edge_b, mask, mask_emb, e, e_bf);

  for (int l = 0; l < L_LAYERS; ++l) {
    size_t wo = (size_t)l * H * H;
    size_t bo = (size_t)l * H;
    k_gemm<0><<<dim3(24, 8), 256, 0, stream>>>(x_bf, WT4 + (size_t)l * 1024 * H, V_NODES, b4 + l * 1024,
                                               nullptr, nullptr, XW, nullptr);
    k_layer_edge<<<E_EDGES / 64, 512, 0, stream>>>(e_bf, WTC + wo, C_b + bo, ei_col, XW,
                                                   nh_g + bo, nh_b + bo, ne_g + bo, ne_b + bo, tvec + bo,
                                                   plo_g + bo, plo_b + bo, x, x_bf, pe_b);
    k_gemm<2><<<dim3(E_EDGES / 128, 2), 256, 0, stream>>>(pe_b, WTplo + wo, E_EDGES, plo_b2 + bo,
                                                          nullptr, nullptr, e, e_bf);
  }

  hipMemsetAsync(gn_sums, 0, 512 * sizeof(double), stream);
  k_gn_stats<<<512, 256, 0, stream>>>(e, gn_sums);
  k_gn_finalize<<<1, 64, 0, stream>>>(gn_sums, gstats);
  k_head<<<E_EDGES / 4, 256, 0, stream>>>(e, gstats, gn_g, gn_b, out_w, out_b, out2);
}